// Round 4
// baseline (1558.030 us; speedup 1.0000x reference)
//
#include <hip/hip_runtime.h>
#include <cstdint>

// HEADS=16, DIM=1024, SEQ=512, MEM=512, CMEM=128, RATIO=4, DIM_H=64, b=8, kv_len=1152

typedef __bf16 bf16;
typedef __bf16 bf16x4 __attribute__((ext_vector_type(4)));
typedef __bf16 bf16x8 __attribute__((ext_vector_type(8)));
typedef float  f32x4  __attribute__((ext_vector_type(4)));

// ---------------------------------------------------------------------------
// MFMA GEMM: C[M,N] = A[M,K] @ B[K,N], tile 128x128, BK=32, 4 waves.
// A: fp32 row-major (AMODE0) or concat-gather rows of cmem/mem/x (AMODE1).
// B: bf16 BT layout [N][K] (BMODE2).
// EPI: 0 normal(+bias), 3 fp32 C + bf16 vT secondary for cols>=1024 (row mod vrows).
// ---------------------------------------------------------------------------
template<int AMODE, int BMODE, int EPI>
__global__ __launch_bounds__(256)
void mfma_gemm(const float* __restrict__ A, const float* __restrict__ B1,
               const bf16* __restrict__ B2, float* __restrict__ C, bf16* __restrict__ vT,
               int N, int K, int lda, int ldbt, int ldc,
               long a_s0, long a_s1, long b_s0, long b_s1, long c_s0, long c_s1,
               const float* __restrict__ bias, int vrows,
               const float* __restrict__ gcmem, const float* __restrict__ gmem,
               const float* __restrict__ gx)
{
    int z = blockIdx.z;
    int zb = z >> 4, zh = z & 15;
    const float* Ab  = A  ? (A  + zb * a_s0 + zh * a_s1) : nullptr;
    const bf16*  Bb2 = B2 ? (B2 + zb * b_s0 + zh * b_s1) : nullptr;
    float* Cb = C + zb * c_s0 + zh * c_s1;

    int row0 = blockIdx.y * 128, col0 = blockIdx.x * 128;
    int tid = threadIdx.x;

    __shared__ bf16 As[128][72];
    __shared__ bf16 Bs[128][72];

    int r_ = tid >> 3;            // 0..31
    int c4 = (tid & 7) * 4;       // A k-chunk (floats)
    const float* aptr[4];
#pragma unroll
    for (int jj = 0; jj < 4; jj++) {
        int gr = row0 + r_ + 32 * jj;
        if (AMODE == 0) {
            aptr[jj] = Ab + (long)gr * lda;
        } else {
            int bb = gr / 1152, rr = gr - bb * 1152;
            aptr[jj] = (rr < 128) ? (gcmem + ((long)bb * 128 + rr) * 1024)
                     : (rr < 640) ? (gmem + ((long)bb * 512 + (rr - 128)) * 1024)
                                  : (gx   + ((long)bb * 512 + (rr - 640)) * 1024);
        }
    }
    const bf16* bptr2[2];
    int rn_ = tid >> 2;           // 0..63
    int c8  = (tid & 3) * 8;      // B2 k-chunk (bf16)
#pragma unroll
    for (int jj = 0; jj < 2; jj++) {
        int gc = col0 + rn_ + 64 * jj;
        bptr2[jj] = (gc < N) ? (Bb2 + (long)gc * ldbt + c8) : nullptr;
    }

    int lane = tid & 63, wid = tid >> 6;
    int wr = wid >> 1, wc = wid & 1;
    int fr = lane & 15, fq = lane >> 4;

    f32x4 acc[4][4];
#pragma unroll
    for (int i = 0; i < 4; i++)
#pragma unroll
        for (int j = 0; j < 4; j++) acc[i][j] = (f32x4){0.f, 0.f, 0.f, 0.f};

    for (int k0 = 0; k0 < K; k0 += 32) {
#pragma unroll
        for (int jj = 0; jj < 4; jj++) {
            float4 f = *(const float4*)(aptr[jj] + k0 + c4);
            bf16x4 h = { (bf16)f.x, (bf16)f.y, (bf16)f.z, (bf16)f.w };
            *(bf16x4*)&As[r_ + 32 * jj][c4] = h;
        }
#pragma unroll
        for (int jj = 0; jj < 2; jj++) {
            bf16x8 v = {};
            if (bptr2[jj]) v = *(const bf16x8*)(bptr2[jj] + k0);
            *(bf16x8*)&Bs[rn_ + 64 * jj][c8] = v;
        }
        __syncthreads();

        bf16x8 af[4], bfv[4];
#pragma unroll
        for (int i = 0; i < 4; i++)
            af[i] = *(const bf16x8*)&As[wr * 64 + i * 16 + fr][fq * 8];
#pragma unroll
        for (int j = 0; j < 4; j++)
            bfv[j] = *(const bf16x8*)&Bs[wc * 64 + j * 16 + fr][fq * 8];
#pragma unroll
        for (int i = 0; i < 4; i++)
#pragma unroll
            for (int j = 0; j < 4; j++)
                acc[i][j] = __builtin_amdgcn_mfma_f32_16x16x32_bf16(af[i], bfv[j], acc[i][j], 0, 0, 0);
        __syncthreads();
    }

#pragma unroll
    for (int i = 0; i < 4; i++) {
#pragma unroll
        for (int j = 0; j < 4; j++) {
#pragma unroll
            for (int g = 0; g < 4; g++) {
                int r = row0 + wr * 64 + i * 16 + fq * 4 + g;
                int c = col0 + wc * 64 + j * 16 + fr;
                float v = acc[i][j][g];
                if (EPI == 0) {
                    if (c < N) {
                        if (bias) v += bias[c];
                        Cb[(long)r * ldc + c] = v;
                    }
                } else { // EPI == 3
                    Cb[(long)r * ldc + c] = v;
                    if (c >= 1024) {
                        int d = c - 1024; int hh = d >> 6; d &= 63;
                        int bb = r / vrows; int j2 = r - bb * vrows;
                        vT[(((long)(bb * 16 + hh)) * 64 + d) * vrows + j2] = (bf16)v;
                    }
                }
            }
        }
    }
}

// fp32 [R][C] -> bf16 [C][R]
__global__ __launch_bounds__(256)
void transpose_cast(const float* __restrict__ in, bf16* __restrict__ out, int R, int C)
{
    __shared__ float t[32][33];
    int c0 = blockIdx.x * 32, r0 = blockIdx.y * 32;
    int tx = threadIdx.x & 31, ty = threadIdx.x >> 5;
#pragma unroll
    for (int i = 0; i < 32; i += 8)
        t[ty + i][tx] = in[(long)(r0 + ty + i) * C + c0 + tx];
    __syncthreads();
#pragma unroll
    for (int i = 0; i < 32; i += 8)
        out[(long)(c0 + ty + i) * R + r0 + tx] = (bf16)t[tx][ty + i];
}

// conv_w [o][i][r] -> bf16 [o][r*1024+i]
__global__ __launch_bounds__(256)
void convw_cast(const float* __restrict__ cw, bf16* __restrict__ out)
{
    long o = blockIdx.x;
    const float* src = cw + o * 4096;
    bf16* dst = out + o * 4096;
    for (int d = threadIdx.x; d < 4096; d += 256)
        dst[d] = (bf16)src[((d & 1023) << 2) | (d >> 10)];
}

// ---------------------------------------------------------------------------
// Fused attention: per (b,h,32 q-rows): S = 0.125*(q@k^T + shifted q@pe^T),
// full-row softmax (S resident in LDS bf16), write fp32 weights, PV -> oat.
// 512 threads = 8 waves. LDS ~113 KB -> 1 block/CU.
// ---------------------------------------------------------------------------
#define SSTR 1164
#define PBSTR 172

__global__ __launch_bounds__(512)
void attn_fused(const float* __restrict__ q, const float* __restrict__ kvb,
                const float* __restrict__ pe, const bf16* __restrict__ vTb,
                float* __restrict__ weights, float* __restrict__ oat)
{
    int z = blockIdx.y;              // b*16 + h
    int b = z >> 4, h = z & 15;
    int r0 = blockIdx.x * 32;
    int tid = threadIdx.x;
    int lane = tid & 63, wid = tid >> 6;
    int fr = lane & 15, fq = lane >> 4;

    __shared__ bf16 S[32 * SSTR];        // 74.5 KB
    __shared__ bf16 qs[32][72];          // 4.6 KB
    __shared__ bf16 stage[160 * 72];     // 23 KB: pe band / k chunk / vT chunk
    __shared__ bf16 pband[32][PBSTR];    // 11 KB

    // stage q (32 x 64)
    {
        int rr = tid >> 4, d4 = (tid & 15) * 4;
        float4 f = *(const float4*)&q[((long)(b * 512 + r0 + rr)) * 1024 + h * 64 + d4];
        bf16x4 hv = { (bf16)f.x, (bf16)f.y, (bf16)f.z, (bf16)f.w };
        *(bf16x4*)&qs[rr][d4] = hv;
    }
    __syncthreads();

    // preload A fragments: afr[rt][ks]
    bf16x8 afr[2][2];
#pragma unroll
    for (int rt = 0; rt < 2; rt++)
#pragma unroll
        for (int ks = 0; ks < 2; ks++)
            afr[rt][ks] = *(const bf16x8*)&qs[rt * 16 + fr][ks * 32 + fq * 8];

    // ---------------- S build: 9 chunks of 128 cols ----------------
    for (int ch = 0; ch < 9; ch++) {
        int c0 = ch * 128;
        int jb0 = c0 + 480 - r0;

        __syncthreads();   // pband consumed by prev chunk; stage free
        // stage pe band (160 x 64)
#pragma unroll
        for (int t = 0; t < 5; t++) {
            int e = tid + 512 * t; int u = e >> 4, d4 = (e & 15) * 4;
            int j = jb0 + u;
            float4 f = make_float4(0.f, 0.f, 0.f, 0.f);
            if (j < 1152) f = *(const float4*)&pe[((long)h * 1152 + j) * 64 + d4];
            bf16x4 hv = { (bf16)f.x, (bf16)f.y, (bf16)f.z, (bf16)f.w };
            *(bf16x4*)&stage[u * 72 + d4] = hv;
        }
        __syncthreads();
        // pos MFMA: 20 tiles (2 row x 10 band cols)
        for (int t = wid; t < 20; t += 8) {
            int rt = t / 10, ct = t % 10;
            f32x4 a = (f32x4){0.f, 0.f, 0.f, 0.f};
#pragma unroll
            for (int ks = 0; ks < 2; ks++) {
                bf16x8 bv = *(const bf16x8*)&stage[(ct * 16 + fr) * 72 + ks * 32 + fq * 8];
                a = __builtin_amdgcn_mfma_f32_16x16x32_bf16(afr[rt][ks], bv, a, 0, 0, 0);
            }
#pragma unroll
            for (int g = 0; g < 4; g++)
                pband[rt * 16 + fq * 4 + g][ct * 16 + fr] = (bf16)a[g];
        }
        __syncthreads();
        // stage k chunk (128 x 64)
#pragma unroll
        for (int t = 0; t < 4; t++) {
            int e = tid + 512 * t; int jj = e >> 4, d4 = (e & 15) * 4;
            float4 f = *(const float4*)&kvb[((long)(b * 1152 + c0 + jj)) * 2048 + h * 64 + d4];
            bf16x4 hv = { (bf16)f.x, (bf16)f.y, (bf16)f.z, (bf16)f.w };
            *(bf16x4*)&stage[jj * 72 + d4] = hv;
        }
        __syncthreads();
        // QK MFMA + shifted pos add -> S
        for (int t = wid; t < 16; t += 8) {
            int rt = t >> 3, ct = t & 7;
            f32x4 a = (f32x4){0.f, 0.f, 0.f, 0.f};
#pragma unroll
            for (int ks = 0; ks < 2; ks++) {
                bf16x8 bv = *(const bf16x8*)&stage[(ct * 16 + fr) * 72 + ks * 32 + fq * 8];
                a = __builtin_amdgcn_mfma_f32_16x16x32_bf16(afr[rt][ks], bv, a, 0, 0, 0);
            }
#pragma unroll
            for (int g = 0; g < 4; g++) {
                int rr = rt * 16 + fq * 4 + g, cc = ct * 16 + fr;
                int u = cc + 31 - rr;
                float v = 0.125f * (a[g] + (float)pband[rr][u]);
                S[rr * SSTR + c0 + cc] = (bf16)v;
            }
        }
    }
    __syncthreads();

    // ---------------- softmax: 8 waves x 4 rows ----------------
    {
        float ebuf[18];
        for (int rw = 0; rw < 4; rw++) {
            int row = wid * 4 + rw;
            float m = -3.4e38f;
#pragma unroll
            for (int k = 0; k < 18; k++) {
                float v = (float)S[row * SSTR + lane + 64 * k];
                ebuf[k] = v; m = fmaxf(m, v);
            }
#pragma unroll
            for (int off = 32; off; off >>= 1) m = fmaxf(m, __shfl_xor(m, off, 64));
            float sm = 0.f;
#pragma unroll
            for (int k = 0; k < 18; k++) { float e = __expf(ebuf[k] - m); ebuf[k] = e; sm += e; }
#pragma unroll
            for (int off = 32; off; off >>= 1) sm += __shfl_xor(sm, off, 64);
            float inv = 1.f / sm;
            long wbase = ((long)z * 512 + r0 + row) * 1152 + lane;
#pragma unroll
            for (int k = 0; k < 18; k++) {
                float p = ebuf[k] * inv;
                weights[wbase + 64 * k] = p;
                S[row * SSTR + lane + 64 * k] = (bf16)p;
            }
        }
    }
    __syncthreads();

    // ---------------- PV: O = P @ V ----------------
    int rt = wid >> 2, dt = wid & 3;     // 8 tiles: 2 row x 4 dcol
    f32x4 oacc = (f32x4){0.f, 0.f, 0.f, 0.f};
    for (int ch = 0; ch < 9; ch++) {
        int c0 = ch * 128;
        // stage vT chunk (64 d x 128 j), stride 136
#pragma unroll
        for (int t = 0; t < 2; t++) {
            int e = tid + 512 * t; int d = e >> 4, j8 = (e & 15) * 8;
            *(bf16x8*)&stage[d * 136 + j8] =
                *(const bf16x8*)&vTb[((long)z * 64 + d) * 1152 + c0 + j8];
        }
        __syncthreads();
#pragma unroll
        for (int ks = 0; ks < 4; ks++) {
            bf16x8 pa = *(const bf16x8*)&S[(rt * 16 + fr) * SSTR + c0 + ks * 32 + fq * 8];
            bf16x8 vb = *(const bf16x8*)&stage[(dt * 16 + fr) * 136 + ks * 32 + fq * 8];
            oacc = __builtin_amdgcn_mfma_f32_16x16x32_bf16(pa, vb, oacc, 0, 0, 0);
        }
        __syncthreads();
    }
#pragma unroll
    for (int g = 0; g < 4; g++)
        oat[((long)(b * 512 + r0 + rt * 16 + fq * 4 + g)) * 1024 + h * 64 + dt * 16 + fr] = oacc[g];
}

// ---------------------------------------------------------------------------
// Fused MFMA aux loss (unchanged, verified round 3)
// ---------------------------------------------------------------------------
__global__ __launch_bounds__(256)
void aux_mfma_kernel(const float* __restrict__ q, const float* __restrict__ kvb,
                     const float* __restrict__ ckv,
                     const bf16* __restrict__ vTb, const bf16* __restrict__ cvT,
                     float* __restrict__ partials)
{
    int z = blockIdx.y;
    int b = z >> 4, h = z & 15;
    int r0 = blockIdx.x * 128;
    int tid = threadIdx.x;
    int lane = tid & 63, wid = tid >> 6;
    int fr = lane & 15, fq = lane >> 4;

    __shared__ bf16 qs[128][72];
    __shared__ bf16 upool[128 * 136];
    __shared__ bf16 vt[64][136];
    __shared__ float wred[4];

#pragma unroll
    for (int t = 0; t < 8; t++) {
        int e = tid + 256 * t; int rr = e >> 4, c4 = (e & 15) * 4;
        float4 f = *(const float4*)&q[((long)(b * 512 + r0 + rr)) * 1024 + h * 64 + c4];
        bf16x4 hv = { (bf16)f.x, (bf16)f.y, (bf16)f.z, (bf16)f.w };
        *(bf16x4*)&qs[rr][c4] = hv;
    }

    float o1[2][4][4];
    f32x4 oaccv[2][4];
    float mrow[2][4], lrow[2][4];
    f32x4 sacc[2][8];
    float local = 0.f;

    for (int pass = 0; pass < 2; pass++) {
#pragma unroll
        for (int i = 0; i < 2; i++)
#pragma unroll
            for (int g = 0; g < 4; g++) { mrow[i][g] = -3.4e38f; lrow[i][g] = 0.f; }
#pragma unroll
        for (int i = 0; i < 2; i++)
#pragma unroll
            for (int jd = 0; jd < 4; jd++) oaccv[i][jd] = (f32x4){0.f, 0.f, 0.f, 0.f};

        int nchunk = pass ? 1 : 4;
        for (int jt = 0; jt < nchunk; jt++) {
            __syncthreads();
            if (pass == 0) {
                long base = (long)(b * 1152 + 128 + jt * 128);
#pragma unroll
                for (int t = 0; t < 8; t++) {
                    int e = tid + 256 * t; int j = e >> 4, c4 = (e & 15) * 4;
                    float4 f = *(const float4*)&kvb[(base + j) * 2048 + h * 64 + c4];
                    bf16x4 hv = { (bf16)f.x, (bf16)f.y, (bf16)f.z, (bf16)f.w };
                    *(bf16x4*)&upool[j * 72 + c4] = hv;
                }
#pragma unroll
                for (int t = 0; t < 4; t++) {
                    int e = tid + 256 * t; int d = e >> 4, j8 = (e & 15) * 8;
                    *(bf16x8*)&vt[d][j8] =
                        *(const bf16x8*)&vTb[((long)z * 64 + d) * 1152 + 128 + jt * 128 + j8];
                }
            } else {
#pragma unroll
                for (int t = 0; t < 8; t++) {
                    int e = tid + 256 * t; int j = e >> 4, c4 = (e & 15) * 4;
                    float4 f = *(const float4*)&ckv[((long)(b * 128 + j)) * 2048 + h * 64 + c4];
                    bf16x4 hv = { (bf16)f.x, (bf16)f.y, (bf16)f.z, (bf16)f.w };
                    *(bf16x4*)&upool[j * 72 + c4] = hv;
                }
#pragma unroll
                for (int t = 0; t < 4; t++) {
                    int e = tid + 256 * t; int d = e >> 4, j8 = (e & 15) * 8;
                    *(bf16x8*)&vt[d][j8] = *(const bf16x8*)&cvT[((long)z * 64 + d) * 128 + j8];
                }
            }
            __syncthreads();

#pragma unroll
            for (int i = 0; i < 2; i++)
#pragma unroll
                for (int j = 0; j < 8; j++) sacc[i][j] = (f32x4){0.f, 0.f, 0.f, 0.f};
#pragma unroll
            for (int s = 0; s < 2; s++) {
                bf16x8 af[2], bfv[8];
#pragma unroll
                for (int i = 0; i < 2; i++)
                    af[i] = *(const bf16x8*)&qs[wid * 32 + i * 16 + fr][s * 32 + fq * 8];
#pragma unroll
                for (int j = 0; j < 8; j++)
                    bfv[j] = *(const bf16x8*)&upool[(j * 16 + fr) * 72 + s * 32 + fq * 8];
#pragma unroll
                for (int i = 0; i < 2; i++)
#pragma unroll
                    for (int j = 0; j < 8; j++)
                        sacc[i][j] = __builtin_amdgcn_mfma_f32_16x16x32_bf16(af[i], bfv[j], sacc[i][j], 0, 0, 0);
            }
            __syncthreads();

#pragma unroll
            for (int i = 0; i < 2; i++) {
#pragma unroll
                for (int g = 0; g < 4; g++) {
                    float mx = -3.4e38f;
#pragma unroll
                    for (int j = 0; j < 8; j++) mx = fmaxf(mx, sacc[i][j][g]);
                    mx *= 0.125f;
#pragma unroll
                    for (int msk = 1; msk <= 8; msk <<= 1) mx = fmaxf(mx, __shfl_xor(mx, msk, 64));
                    float mnew = fmaxf(mrow[i][g], mx);
                    float alpha = __expf(mrow[i][g] - mnew);
                    mrow[i][g] = mnew;
                    float sum = 0.f;
                    int prow = (wid * 32 + i * 16 + fq * 4 + g) * 136;
#pragma unroll
                    for (int j = 0; j < 8; j++) {
                        float p = __expf(sacc[i][j][g] * 0.125f - mnew);
                        sum += p;
                        upool[prow + j * 16 + fr] = (bf16)p;
                    }
#pragma unroll
                    for (int msk = 1; msk <= 8; msk <<= 1) sum += __shfl_xor(sum, msk, 64);
                    lrow[i][g] = lrow[i][g] * alpha + sum;
#pragma unroll
                    for (int jd = 0; jd < 4; jd++) oaccv[i][jd][g] *= alpha;
                }
            }
            __syncthreads();

#pragma unroll
            for (int s2 = 0; s2 < 4; s2++) {
                bf16x8 pa[2], vb[4];
#pragma unroll
                for (int i = 0; i < 2; i++)
                    pa[i] = *(const bf16x8*)&upool[(wid * 32 + i * 16 + fr) * 136 + s2 * 32 + fq * 8];
#pragma unroll
                for (int jd = 0; jd < 4; jd++)
                    vb[jd] = *(const bf16x8*)&vt[jd * 16 + fr][s2 * 32 + fq * 8];
#pragma unroll
                for (int i = 0; i < 2; i++)
#pragma unroll
                    for (int jd = 0; jd < 4; jd++)
                        oaccv[i][jd] = __builtin_amdgcn_mfma_f32_16x16x32_bf16(pa[i], vb[jd], oaccv[i][jd], 0, 0, 0);
            }
        }

        if (pass == 0) {
#pragma unroll
            for (int i = 0; i < 2; i++)
#pragma unroll
                for (int jd = 0; jd < 4; jd++)
#pragma unroll
                    for (int g = 0; g < 4; g++)
                        o1[i][jd][g] = oaccv[i][jd][g] / lrow[i][g];
        } else {
#pragma unroll
            for (int i = 0; i < 2; i++)
#pragma unroll
                for (int jd = 0; jd < 4; jd++)
#pragma unroll
                    for (int g = 0; g < 4; g++) {
                        float dd = o1[i][jd][g] - oaccv[i][jd][g] / lrow[i][g];
                        local += dd * dd;
                    }
        }
    }

#pragma unroll
    for (int off = 32; off; off >>= 1) local += __shfl_xor(local, off, 64);
    if (lane == 0) wred[wid] = local;
    __syncthreads();
    if (tid == 0)
        partials[(long)blockIdx.y * 4 + blockIdx.x] = wred[0] + wred[1] + wred[2] + wred[3];
}

__global__ __launch_bounds__(256)
void aux_reduce_kernel(const float* __restrict__ partials, float* __restrict__ out)
{
    int tid = threadIdx.x;
    __shared__ float wred[4];
    float s = 0.f;
    for (int i = tid; i < 512; i += 256) s += partials[i];
#pragma unroll
    for (int off = 32; off; off >>= 1) s += __shfl_xor(s, off, 64);
    if ((tid & 63) == 0) wred[tid >> 6] = s;
    __syncthreads();
    if (tid == 0) out[0] = (wred[0] + wred[1] + wred[2] + wred[3]) * (1.0f / 4194304.0f);
}

__global__ __launch_bounds__(256)
void copy_kernel(float* __restrict__ dst, const float* __restrict__ src, int n4)
{
    int i = blockIdx.x * 256 + threadIdx.x;
    int stride = gridDim.x * 256;
    for (; i < n4; i += stride)
        reinterpret_cast<float4*>(dst)[i] = reinterpret_cast<const float4*>(src)[i];
}

extern "C" void kernel_launch(void* const* d_in, const int* in_sizes, int n_in,
                              void* d_out, int out_size, void* d_ws, size_t ws_size,
                              hipStream_t stream)
{
    const float* x      = (const float*)d_in[0];
    const float* mem    = (const float*)d_in[1];
    const float* cmem   = (const float*)d_in[2];
    const float* pe     = (const float*)d_in[3];
    const float* Wq     = (const float*)d_in[4];
    const float* Wkv    = (const float*)d_in[5];
    const float* Wout   = (const float*)d_in[6];
    const float* bout   = (const float*)d_in[7];
    const float* conv_w = (const float*)d_in[8];
    const float* conv_b = (const float*)d_in[9];

    float* out_logits  = (float*)d_out;                 // 8*512*1024
    float* out_newmem  = out_logits + 4194304;          // 8*512*1024
    float* out_newcmem = out_newmem + 4194304;          // 8*128*1024
    float* out_aux     = out_newcmem + 1048576;         // 1
    float* out_weights = out_aux + 1;                   // 8*16*512*1152

    float* ws       = (float*)d_ws;
    float* q        = ws;                    // 4,194,304 f
    float* kvb      = q + 4194304;           // 18,874,368 f
    float* ckv      = kvb + 18874368;        // 2,097,152 f
    float* oat      = ckv + 2097152;         // 4,194,304 f
    float* partials = oat + 4194304;         // 512 f (pad 4096)
    bf16* bws      = (bf16*)(partials + 4096);
    bf16* WqTb     = bws;                    // 1,048,576
    bf16* WkvTb    = WqTb + 1048576;         // 2,097,152
    bf16* WoutTb   = WkvTb + 2097152;        // 1,048,576
    bf16* convwTb  = WoutTb + 1048576;       // 4,194,304
    bf16* vTb      = convwTb + 4194304;      // 9,437,184
    bf16* cvT      = vTb + 9437184;          // 1,048,576

    dim3 blk(256);

    transpose_cast<<<dim3(32, 32), blk, 0, stream>>>(Wq, WqTb, 1024, 1024);
    transpose_cast<<<dim3(64, 32), blk, 0, stream>>>(Wkv, WkvTb, 1024, 2048);
    transpose_cast<<<dim3(32, 32), blk, 0, stream>>>(Wout, WoutTb, 1024, 1024);
    convw_cast<<<dim3(1024), blk, 0, stream>>>(conv_w, convwTb);

    // q = x @ Wq
    mfma_gemm<0, 2, 0><<<dim3(8, 32, 1), blk, 0, stream>>>(
        x, nullptr, WqTb, q, nullptr, 1024, 1024, 1024, 1024, 1024,
        0, 0, 0, 0, 0, 0, nullptr, 0, nullptr, nullptr, nullptr);

    // kv = concat(cmem,mem,x) @ Wkv + vT bf16 secondary
    mfma_gemm<1, 2, 3><<<dim3(16, 72, 1), blk, 0, stream>>>(
        nullptr, nullptr, WkvTb, kvb, vTb, 2048, 1024, 1024, 1024, 2048,
        0, 0, 0, 0, 0, 0, nullptr, 1152, cmem, mem, x);

    // new_cmem = mem[1024x4096] @ convwT + conv_b
    mfma_gemm<0, 2, 0><<<dim3(8, 8, 1), blk, 0, stream>>>(
        mem, nullptr, convwTb, out_newcmem, nullptr, 1024, 4096, 4096, 4096, 1024,
        0, 0, 0, 0, 0, 0, conv_b, 0, nullptr, nullptr, nullptr);

    // ckv = new_cmem @ Wkv + cvT secondary (vrows=128)
    mfma_gemm<0, 2, 3><<<dim3(16, 8, 1), blk, 0, stream>>>(
        out_newcmem, nullptr, WkvTb, ckv, cvT, 2048, 1024, 1024, 1024, 2048,
        0, 0, 0, 0, 0, 0, nullptr, 128, nullptr, nullptr, nullptr);

    // fused attention: dots(+pos shift) -> softmax -> weights + oat
    attn_fused<<<dim3(16, 128), dim3(512), 0, stream>>>(q, kvb, pe, vTb, out_weights, oat);

    // logits = oat @ Wout + bout
    mfma_gemm<0, 2, 0><<<dim3(8, 32, 1), blk, 0, stream>>>(
        oat, nullptr, WoutTb, out_logits, nullptr, 1024, 1024, 1024, 1024, 1024,
        0, 0, 0, 0, 0, 0, bout, 0, nullptr, nullptr, nullptr);

    // new_mem = x
    copy_kernel<<<dim3(4096), blk, 0, stream>>>(out_newmem, x, 1048576);

    // aux loss
    aux_mfma_kernel<<<dim3(4, 128), blk, 0, stream>>>(q, kvb, ckv, vTb, cvT, partials);
    aux_reduce_kernel<<<dim3(1), blk, 0, stream>>>(partials, out_aux);
}

// Round 5
// 995.010 us; speedup vs baseline: 1.5658x; 1.5658x over previous
//
#include <hip/hip_runtime.h>
#include <cstdint>

// HEADS=16, DIM=1024, SEQ=512, MEM=512, CMEM=128, RATIO=4, DIM_H=64, b=8, kv_len=1152

typedef __bf16 bf16;
typedef __bf16 bf16x4 __attribute__((ext_vector_type(4)));
typedef __bf16 bf16x8 __attribute__((ext_vector_type(8)));
typedef float  f32x4  __attribute__((ext_vector_type(4)));

// ---------------------------------------------------------------------------
// MFMA GEMM: C[M,N] = A[M,K] @ B[K,N], tile 128x128, BK=32, 4 waves.
// A: fp32 row-major (AMODE0) or concat-gather rows of cmem/mem/x (AMODE1).
// B: bf16 BT layout [N][K].
// EPI 0: fp32 C (+bias)
// EPI 4: bf16-only output: outB[r*ldc + c]
// EPI 5: bf16 outB[r*1024+c] for c<1024, bf16 vT[((r/vrows)*16+h)*64+d][j] for c>=1024
// ---------------------------------------------------------------------------
template<int AMODE, int EPI>
__global__ __launch_bounds__(256)
void mfma_gemm(const float* __restrict__ A, const bf16* __restrict__ B2,
               float* __restrict__ C, bf16* __restrict__ outB, bf16* __restrict__ vT,
               int N, int K, int lda, int ldbt, int ldc,
               const float* __restrict__ bias, int vrows,
               const float* __restrict__ gcmem, const float* __restrict__ gmem,
               const float* __restrict__ gx)
{
    int row0 = blockIdx.y * 128, col0 = blockIdx.x * 128;
    int tid = threadIdx.x;

    __shared__ bf16 As[128][72];
    __shared__ bf16 Bs[128][72];

    int r_ = tid >> 3;            // 0..31
    int c4 = (tid & 7) * 4;       // A k-chunk (floats)
    const float* aptr[4];
#pragma unroll
    for (int jj = 0; jj < 4; jj++) {
        int gr = row0 + r_ + 32 * jj;
        if (AMODE == 0) {
            aptr[jj] = A + (long)gr * lda;
        } else {
            int bb = gr / 1152, rr = gr - bb * 1152;
            aptr[jj] = (rr < 128) ? (gcmem + ((long)bb * 128 + rr) * 1024)
                     : (rr < 640) ? (gmem + ((long)bb * 512 + (rr - 128)) * 1024)
                                  : (gx   + ((long)bb * 512 + (rr - 640)) * 1024);
        }
    }
    const bf16* bptr2[2];
    int rn_ = tid >> 2;           // 0..63
    int c8  = (tid & 3) * 8;      // B k-chunk (bf16)
#pragma unroll
    for (int jj = 0; jj < 2; jj++) {
        int gc = col0 + rn_ + 64 * jj;
        bptr2[jj] = (gc < N) ? (B2 + (long)gc * ldbt + c8) : nullptr;
    }

    int lane = tid & 63, wid = tid >> 6;
    int wr = wid >> 1, wc = wid & 1;
    int fr = lane & 15, fq = lane >> 4;

    f32x4 acc[4][4];
#pragma unroll
    for (int i = 0; i < 4; i++)
#pragma unroll
        for (int j = 0; j < 4; j++) acc[i][j] = (f32x4){0.f, 0.f, 0.f, 0.f};

    for (int k0 = 0; k0 < K; k0 += 32) {
#pragma unroll
        for (int jj = 0; jj < 4; jj++) {
            float4 f = *(const float4*)(aptr[jj] + k0 + c4);
            bf16x4 h = { (bf16)f.x, (bf16)f.y, (bf16)f.z, (bf16)f.w };
            *(bf16x4*)&As[r_ + 32 * jj][c4] = h;
        }
#pragma unroll
        for (int jj = 0; jj < 2; jj++) {
            bf16x8 v = {};
            if (bptr2[jj]) v = *(const bf16x8*)(bptr2[jj] + k0);
            *(bf16x8*)&Bs[rn_ + 64 * jj][c8] = v;
        }
        __syncthreads();

        bf16x8 af[4], bfv[4];
#pragma unroll
        for (int i = 0; i < 4; i++)
            af[i] = *(const bf16x8*)&As[wr * 64 + i * 16 + fr][fq * 8];
#pragma unroll
        for (int j = 0; j < 4; j++)
            bfv[j] = *(const bf16x8*)&Bs[wc * 64 + j * 16 + fr][fq * 8];
#pragma unroll
        for (int i = 0; i < 4; i++)
#pragma unroll
            for (int j = 0; j < 4; j++)
                acc[i][j] = __builtin_amdgcn_mfma_f32_16x16x32_bf16(af[i], bfv[j], acc[i][j], 0, 0, 0);
        __syncthreads();
    }

#pragma unroll
    for (int i = 0; i < 4; i++) {
#pragma unroll
        for (int j = 0; j < 4; j++) {
#pragma unroll
            for (int g = 0; g < 4; g++) {
                int r = row0 + wr * 64 + i * 16 + fq * 4 + g;
                int c = col0 + wc * 64 + j * 16 + fr;
                float v = acc[i][j][g];
                if (EPI == 0) {
                    if (c < N) {
                        if (bias) v += bias[c];
                        C[(long)r * ldc + c] = v;
                    }
                } else if (EPI == 4) {
                    if (c < N) outB[(long)r * ldc + c] = (bf16)v;
                } else { // EPI == 5
                    if (c < 1024) {
                        outB[(long)r * 1024 + c] = (bf16)v;
                    } else {
                        int d = c - 1024; int hh = d >> 6; d &= 63;
                        int bb = r / vrows; int j2 = r - bb * vrows;
                        vT[(((long)(bb * 16 + hh)) * 64 + d) * vrows + j2] = (bf16)v;
                    }
                }
            }
        }
    }
}

// fp32 [R][C] -> bf16 [C][R]
__global__ __launch_bounds__(256)
void transpose_cast(const float* __restrict__ in, bf16* __restrict__ out, int R, int C)
{
    __shared__ float t[32][33];
    int c0 = blockIdx.x * 32, r0 = blockIdx.y * 32;
    int tx = threadIdx.x & 31, ty = threadIdx.x >> 5;
#pragma unroll
    for (int i = 0; i < 32; i += 8)
        t[ty + i][tx] = in[(long)(r0 + ty + i) * C + c0 + tx];
    __syncthreads();
#pragma unroll
    for (int i = 0; i < 32; i += 8)
        out[(long)(c0 + ty + i) * R + r0 + tx] = (bf16)t[tx][ty + i];
}

// conv_w [o][i][r] -> bf16 [o][r*1024+i]
__global__ __launch_bounds__(256)
void convw_cast(const float* __restrict__ cw, bf16* __restrict__ out)
{
    long o = blockIdx.x;
    const float* src = cw + o * 4096;
    bf16* dst = out + o * 4096;
    for (int d = threadIdx.x; d < 4096; d += 256)
        dst[d] = (bf16)src[((d & 1023) << 2) | (d >> 10)];
}

// elementwise fp32 -> bf16 (vectorized by 4)
__global__ __launch_bounds__(256)
void cast_f2b(const float* __restrict__ in, bf16* __restrict__ out, int n4)
{
    int i = blockIdx.x * 256 + threadIdx.x;
    int stride = gridDim.x * 256;
    for (; i < n4; i += stride) {
        float4 f = reinterpret_cast<const float4*>(in)[i];
        bf16x4 h = { (bf16)f.x, (bf16)f.y, (bf16)f.z, (bf16)f.w };
        reinterpret_cast<bf16x4*>(out)[i] = h;
    }
}

// ---------------------------------------------------------------------------
// Fused attention, 16 q-rows per block, 4 waves. All operands bf16 in global,
// fragments loaded directly (no staging cvt). S row resident in LDS.
// ---------------------------------------------------------------------------
#define SSTR 1164

__global__ __launch_bounds__(256)
void attn_fused16(const bf16* __restrict__ qb, const bf16* __restrict__ kb,
                  const bf16* __restrict__ peb, const bf16* __restrict__ vTb,
                  float* __restrict__ weights, float* __restrict__ oat)
{
    int z = blockIdx.y;              // b*16 + h
    int b = z >> 4, h = z & 15;
    int r0 = blockIdx.x * 16;
    int tid = threadIdx.x;
    int lane = tid & 63, wid = tid >> 6;
    int fr = lane & 15, fq = lane >> 4;

    __shared__ bf16 S[16 * SSTR];      // 36.4 KB
    __shared__ bf16 pband[16][152];    // 4.75 KB

    // q fragments direct from global (compile-time register indices only)
    bf16x8 afr[2];
#pragma unroll
    for (int ks = 0; ks < 2; ks++)
        afr[ks] = *(const bf16x8*)&qb[((long)(b * 512 + r0 + fr)) * 1024 + h * 64 + ks * 32 + fq * 8];

    for (int ch = 0; ch < 9; ch++) {
        int c0 = ch * 128;
        int jb0 = c0 + 496 - r0;

        // pos tiles: band of 144 cols -> 9 tiles over 4 waves
#pragma unroll
        for (int tt = 0; tt < 3; tt++) {
            int ct = wid + 4 * tt;
            if (ct < 9) {
                f32x4 a = (f32x4){0.f, 0.f, 0.f, 0.f};
                int j = jb0 + ct * 16 + fr;
#pragma unroll
                for (int ks = 0; ks < 2; ks++) {
                    bf16x8 bv = {};
                    if (j < 1152)
                        bv = *(const bf16x8*)&peb[((long)(h * 1152 + j)) * 64 + ks * 32 + fq * 8];
                    a = __builtin_amdgcn_mfma_f32_16x16x32_bf16(afr[ks], bv, a, 0, 0, 0);
                }
#pragma unroll
                for (int g = 0; g < 4; g++) pband[fq * 4 + g][ct * 16 + fr] = (bf16)a[g];
            }
        }
        __syncthreads();

        // qk tiles: 8 over 4 waves, + shifted pos add -> S
#pragma unroll
        for (int tt = 0; tt < 2; tt++) {
            int ct = wid * 2 + tt;
            f32x4 a = (f32x4){0.f, 0.f, 0.f, 0.f};
            long krow = (long)(b * 1152 + c0 + ct * 16 + fr);
#pragma unroll
            for (int ks = 0; ks < 2; ks++) {
                bf16x8 bv = *(const bf16x8*)&kb[krow * 1024 + h * 64 + ks * 32 + fq * 8];
                a = __builtin_amdgcn_mfma_f32_16x16x32_bf16(afr[ks], bv, a, 0, 0, 0);
            }
#pragma unroll
            for (int g = 0; g < 4; g++) {
                int rr = fq * 4 + g, cc = ct * 16 + fr;
                S[rr * SSTR + c0 + cc] = (bf16)(0.125f * (a[g] + (float)pband[rr][cc + 15 - rr]));
            }
        }
        __syncthreads();
    }

    // softmax: 4 waves x 4 rows
    for (int rw = 0; rw < 4; rw++) {
        int row = wid * 4 + rw;
        float ebuf[18];
        float m = -3.4e38f;
#pragma unroll
        for (int k = 0; k < 18; k++) {
            float v = (float)S[row * SSTR + lane + 64 * k];
            ebuf[k] = v; m = fmaxf(m, v);
        }
#pragma unroll
        for (int off = 32; off; off >>= 1) m = fmaxf(m, __shfl_xor(m, off, 64));
        float sm = 0.f;
#pragma unroll
        for (int k = 0; k < 18; k++) { float e = __expf(ebuf[k] - m); ebuf[k] = e; sm += e; }
#pragma unroll
        for (int off = 32; off; off >>= 1) sm += __shfl_xor(sm, off, 64);
        float inv = 1.f / sm;
        long wbase = ((long)z * 512 + r0 + row) * 1152 + lane;
#pragma unroll
        for (int k = 0; k < 18; k++) {
            float p = ebuf[k] * inv;
            weights[wbase + 64 * k] = p;
            S[row * SSTR + lane + 64 * k] = (bf16)p;
        }
    }
    __syncthreads();

    // PV: wave wid owns d-tile dt=wid (16 cols of 64)
    f32x4 oacc = (f32x4){0.f, 0.f, 0.f, 0.f};
    int dt = wid;
    for (int ch = 0; ch < 9; ch++) {
        int c0 = ch * 128;
#pragma unroll
        for (int ks = 0; ks < 4; ks++) {
            bf16x8 pa = *(const bf16x8*)&S[fr * SSTR + c0 + ks * 32 + fq * 8];
            bf16x8 vb = *(const bf16x8*)&vTb[((long)z * 64 + dt * 16 + fr) * 1152 + c0 + ks * 32 + fq * 8];
            oacc = __builtin_amdgcn_mfma_f32_16x16x32_bf16(pa, vb, oacc, 0, 0, 0);
        }
    }
#pragma unroll
    for (int g = 0; g < 4; g++)
        oat[((long)(b * 512 + r0 + fq * 4 + g)) * 1024 + h * 64 + dt * 16 + fr] = oacc[g];
}

// ---------------------------------------------------------------------------
// Fused MFMA aux loss (bf16-staged sources)
// ---------------------------------------------------------------------------
__global__ __launch_bounds__(256)
void aux_mfma_kernel(const bf16* __restrict__ qb, const bf16* __restrict__ kb,
                     const bf16* __restrict__ ckb,
                     const bf16* __restrict__ vTb, const bf16* __restrict__ cvT,
                     float* __restrict__ partials)
{
    int z = blockIdx.y;
    int b = z >> 4, h = z & 15;
    int r0 = blockIdx.x * 128;
    int tid = threadIdx.x;
    int lane = tid & 63, wid = tid >> 6;
    int fr = lane & 15, fq = lane >> 4;

    __shared__ bf16 qs[128][72];
    __shared__ bf16 upool[128 * 136];
    __shared__ bf16 vt[64][136];
    __shared__ float wred[4];

#pragma unroll
    for (int t = 0; t < 4; t++) {
        int e = tid + 256 * t; int rr = e >> 3, c8 = (e & 7) * 8;
        *(bf16x8*)&qs[rr][c8] = *(const bf16x8*)&qb[((long)(b * 512 + r0 + rr)) * 1024 + h * 64 + c8];
    }

    float o1[2][4][4];
    f32x4 oaccv[2][4];
    float mrow[2][4], lrow[2][4];
    f32x4 sacc[2][8];
    float local = 0.f;

    for (int pass = 0; pass < 2; pass++) {
#pragma unroll
        for (int i = 0; i < 2; i++)
#pragma unroll
            for (int g = 0; g < 4; g++) { mrow[i][g] = -3.4e38f; lrow[i][g] = 0.f; }
#pragma unroll
        for (int i = 0; i < 2; i++)
#pragma unroll
            for (int jd = 0; jd < 4; jd++) oaccv[i][jd] = (f32x4){0.f, 0.f, 0.f, 0.f};

        int nchunk = pass ? 1 : 4;
        for (int jt = 0; jt < nchunk; jt++) {
            __syncthreads();
            if (pass == 0) {
                long base = (long)(b * 1152 + 128 + jt * 128);
#pragma unroll
                for (int t = 0; t < 4; t++) {
                    int e = tid + 256 * t; int j = e >> 3, c8 = (e & 7) * 8;
                    *(bf16x8*)&upool[j * 72 + c8] = *(const bf16x8*)&kb[(base + j) * 1024 + h * 64 + c8];
                }
#pragma unroll
                for (int t = 0; t < 4; t++) {
                    int e = tid + 256 * t; int d = e >> 4, j8 = (e & 15) * 8;
                    *(bf16x8*)&vt[d][j8] =
                        *(const bf16x8*)&vTb[((long)z * 64 + d) * 1152 + 128 + jt * 128 + j8];
                }
            } else {
#pragma unroll
                for (int t = 0; t < 4; t++) {
                    int e = tid + 256 * t; int j = e >> 3, c8 = (e & 7) * 8;
                    *(bf16x8*)&upool[j * 72 + c8] = *(const bf16x8*)&ckb[((long)(b * 128 + j)) * 1024 + h * 64 + c8];
                }
#pragma unroll
                for (int t = 0; t < 4; t++) {
                    int e = tid + 256 * t; int d = e >> 4, j8 = (e & 15) * 8;
                    *(bf16x8*)&vt[d][j8] = *(const bf16x8*)&cvT[((long)z * 64 + d) * 128 + j8];
                }
            }
            __syncthreads();

#pragma unroll
            for (int i = 0; i < 2; i++)
#pragma unroll
                for (int j = 0; j < 8; j++) sacc[i][j] = (f32x4){0.f, 0.f, 0.f, 0.f};
#pragma unroll
            for (int s = 0; s < 2; s++) {
                bf16x8 af[2], bfv[8];
#pragma unroll
                for (int i = 0; i < 2; i++)
                    af[i] = *(const bf16x8*)&qs[wid * 32 + i * 16 + fr][s * 32 + fq * 8];
#pragma unroll
                for (int j = 0; j < 8; j++)
                    bfv[j] = *(const bf16x8*)&upool[(j * 16 + fr) * 72 + s * 32 + fq * 8];
#pragma unroll
                for (int i = 0; i < 2; i++)
#pragma unroll
                    for (int j = 0; j < 8; j++)
                        sacc[i][j] = __builtin_amdgcn_mfma_f32_16x16x32_bf16(af[i], bfv[j], sacc[i][j], 0, 0, 0);
            }
            __syncthreads();

#pragma unroll
            for (int i = 0; i < 2; i++) {
#pragma unroll
                for (int g = 0; g < 4; g++) {
                    float mx = -3.4e38f;
#pragma unroll
                    for (int j = 0; j < 8; j++) mx = fmaxf(mx, sacc[i][j][g]);
                    mx *= 0.125f;
#pragma unroll
                    for (int msk = 1; msk <= 8; msk <<= 1) mx = fmaxf(mx, __shfl_xor(mx, msk, 64));
                    float mnew = fmaxf(mrow[i][g], mx);
                    float alpha = __expf(mrow[i][g] - mnew);
                    mrow[i][g] = mnew;
                    float sum = 0.f;
                    int prow = (wid * 32 + i * 16 + fq * 4 + g) * 136;
#pragma unroll
                    for (int j = 0; j < 8; j++) {
                        float p = __expf(sacc[i][j][g] * 0.125f - mnew);
                        sum += p;
                        upool[prow + j * 16 + fr] = (bf16)p;
                    }
#pragma unroll
                    for (int msk = 1; msk <= 8; msk <<= 1) sum += __shfl_xor(sum, msk, 64);
                    lrow[i][g] = lrow[i][g] * alpha + sum;
#pragma unroll
                    for (int jd = 0; jd < 4; jd++) oaccv[i][jd][g] *= alpha;
                }
            }
            __syncthreads();

#pragma unroll
            for (int s2 = 0; s2 < 4; s2++) {
                bf16x8 pa[2], vb[4];
#pragma unroll
                for (int i = 0; i < 2; i++)
                    pa[i] = *(const bf16x8*)&upool[(wid * 32 + i * 16 + fr) * 136 + s2 * 32 + fq * 8];
#pragma unroll
                for (int jd = 0; jd < 4; jd++)
                    vb[jd] = *(const bf16x8*)&vt[jd * 16 + fr][s2 * 32 + fq * 8];
#pragma unroll
                for (int i = 0; i < 2; i++)
#pragma unroll
                    for (int jd = 0; jd < 4; jd++)
                        oaccv[i][jd] = __builtin_amdgcn_mfma_f32_16x16x32_bf16(pa[i], vb[jd], oaccv[i][jd], 0, 0, 0);
            }
        }

        if (pass == 0) {
#pragma unroll
            for (int i = 0; i < 2; i++)
#pragma unroll
                for (int jd = 0; jd < 4; jd++)
#pragma unroll
                    for (int g = 0; g < 4; g++)
                        o1[i][jd][g] = oaccv[i][jd][g] / lrow[i][g];
        } else {
#pragma unroll
            for (int i = 0; i < 2; i++)
#pragma unroll
                for (int jd = 0; jd < 4; jd++)
#pragma unroll
                    for (int g = 0; g < 4; g++) {
                        float dd = o1[i][jd][g] - oaccv[i][jd][g] / lrow[i][g];
                        local += dd * dd;
                    }
        }
    }

#pragma unroll
    for (int off = 32; off; off >>= 1) local += __shfl_xor(local, off, 64);
    if (lane == 0) wred[wid] = local;
    __syncthreads();
    if (tid == 0)
        partials[(long)blockIdx.y * 4 + blockIdx.x] = wred[0] + wred[1] + wred[2] + wred[3];
}

__global__ __launch_bounds__(256)
void aux_reduce_kernel(const float* __restrict__ partials, float* __restrict__ out)
{
    int tid = threadIdx.x;
    __shared__ float wred[4];
    float s = 0.f;
    for (int i = tid; i < 512; i += 256) s += partials[i];
#pragma unroll
    for (int off = 32; off; off >>= 1) s += __shfl_xor(s, off, 64);
    if ((tid & 63) == 0) wred[tid >> 6] = s;
    __syncthreads();
    if (tid == 0) out[0] = (wred[0] + wred[1] + wred[2] + wred[3]) * (1.0f / 4194304.0f);
}

__global__ __launch_bounds__(256)
void copy_kernel(float* __restrict__ dst, const float* __restrict__ src, int n4)
{
    int i = blockIdx.x * 256 + threadIdx.x;
    int stride = gridDim.x * 256;
    for (; i < n4; i += stride)
        reinterpret_cast<float4*>(dst)[i] = reinterpret_cast<const float4*>(src)[i];
}

extern "C" void kernel_launch(void* const* d_in, const int* in_sizes, int n_in,
                              void* d_out, int out_size, void* d_ws, size_t ws_size,
                              hipStream_t stream)
{
    const float* x      = (const float*)d_in[0];
    const float* mem    = (const float*)d_in[1];
    const float* cmem   = (const float*)d_in[2];
    const float* pe     = (const float*)d_in[3];
    const float* Wq     = (const float*)d_in[4];
    const float* Wkv    = (const float*)d_in[5];
    const float* Wout   = (const float*)d_in[6];
    const float* bout   = (const float*)d_in[7];
    const float* conv_w = (const float*)d_in[8];
    const float* conv_b = (const float*)d_in[9];

    float* out_logits  = (float*)d_out;                 // 8*512*1024
    float* out_newmem  = out_logits + 4194304;          // 8*512*1024
    float* out_newcmem = out_newmem + 4194304;          // 8*128*1024
    float* out_aux     = out_newcmem + 1048576;         // 1
    float* out_weights = out_aux + 1;                   // 8*16*512*1152

    float* ws       = (float*)d_ws;
    float* oat      = ws;                    // 4,194,304 f
    float* partials = oat + 4194304;         // 4096 f
    bf16* bws     = (bf16*)(partials + 4096);
    bf16* WqTb    = bws;                     // 1,048,576
    bf16* WkvTb   = WqTb + 1048576;          // 2,097,152
    bf16* WoutTb  = WkvTb + 2097152;         // 1,048,576
    bf16* convwTb = WoutTb + 1048576;        // 4,194,304
    bf16* vTb     = convwTb + 4194304;       // 9,437,184
    bf16* cvT     = vTb + 9437184;           // 1,048,576
    bf16* qb      = cvT + 1048576;           // 4,194,304
    bf16* kb      = qb + 4194304;            // 9,437,184
    bf16* ckb     = kb + 9437184;            // 1,048,576
    bf16* peb     = ckb + 1048576;           // 1,179,648

    dim3 blk(256);

    transpose_cast<<<dim3(32, 32), blk, 0, stream>>>(Wq, WqTb, 1024, 1024);
    transpose_cast<<<dim3(64, 32), blk, 0, stream>>>(Wkv, WkvTb, 1024, 2048);
    transpose_cast<<<dim3(32, 32), blk, 0, stream>>>(Wout, WoutTb, 1024, 1024);
    convw_cast<<<dim3(1024), blk, 0, stream>>>(conv_w, convwTb);
    cast_f2b<<<dim3(1152), blk, 0, stream>>>(pe, peb, 294912);

    // qb = bf16(x @ Wq)
    mfma_gemm<0, 4><<<dim3(8, 32, 1), blk, 0, stream>>>(
        x, WqTb, nullptr, qb, nullptr, 1024, 1024, 1024, 1024, 1024,
        nullptr, 0, nullptr, nullptr, nullptr);

    // kb/vTb = bf16(concat(cmem,mem,x) @ Wkv)
    mfma_gemm<1, 5><<<dim3(16, 72, 1), blk, 0, stream>>>(
        nullptr, WkvTb, nullptr, kb, vTb, 2048, 1024, 1024, 1024, 2048,
        nullptr, 1152, cmem, mem, x);

    // new_cmem = mem[1024x4096] @ convwT + conv_b (fp32 output)
    mfma_gemm<0, 0><<<dim3(8, 8, 1), blk, 0, stream>>>(
        mem, convwTb, out_newcmem, nullptr, nullptr, 1024, 4096, 4096, 4096, 1024,
        conv_b, 0, nullptr, nullptr, nullptr);

    // ckb/cvT = bf16(new_cmem @ Wkv)
    mfma_gemm<0, 5><<<dim3(16, 8, 1), blk, 0, stream>>>(
        out_newcmem, WkvTb, nullptr, ckb, cvT, 2048, 1024, 1024, 1024, 2048,
        nullptr, 128, nullptr, nullptr, nullptr);

    // fused attention: dots(+pos shift) -> softmax -> weights + oat
    attn_fused16<<<dim3(32, 128), blk, 0, stream>>>(qb, kb, peb, vTb, out_weights, oat);

    // logits = oat @ Wout + bout
    mfma_gemm<0, 0><<<dim3(8, 32, 1), blk, 0, stream>>>(
        oat, WoutTb, out_logits, nullptr, nullptr, 1024, 1024, 1024, 1024, 1024,
        bout, 0, nullptr, nullptr, nullptr);

    // new_mem = x
    copy_kernel<<<dim3(4096), blk, 0, stream>>>(out_newmem, x, 1048576);

    // aux loss
    aux_mfma_kernel<<<dim3(4, 128), blk, 0, stream>>>(qb, kb, ckb, vTb, cvT, partials);
    aux_reduce_kernel<<<dim3(1), blk, 0, stream>>>(partials, out_aux);
}

// Round 7
// 945.608 us; speedup vs baseline: 1.6476x; 1.0522x over previous
//
#include <hip/hip_runtime.h>
#include <cstdint>

// HEADS=16, DIM=1024, SEQ=512, MEM=512, CMEM=128, RATIO=4, DIM_H=64, b=8, kv_len=1152

typedef __bf16 bf16;
typedef __bf16 bf16x4 __attribute__((ext_vector_type(4)));
typedef __bf16 bf16x8 __attribute__((ext_vector_type(8)));
typedef float  f32x4  __attribute__((ext_vector_type(4)));

// ---------------------------------------------------------------------------
// MFMA GEMM: C[M,N] = A[M,K] @ B[K,N], tile 128x128, BK=32, 4 waves.
// A: fp32 row-major (AMODE0) or concat-gather rows of cmem/mem/x (AMODE1).
// B: bf16 BT layout [N][K].
// EPI 0: fp32 C (+bias)
// EPI 4: bf16-only output: outB[r*ldc + c]
// EPI 5: bf16 outB[r*1024+c] for c<1024, bf16 vT for c>=1024 (row mod vrows)
// EPI 6: fp32 C (+bias), non-temporal store (output never re-read on device)
// ---------------------------------------------------------------------------
template<int AMODE, int EPI>
__global__ __launch_bounds__(256)
void mfma_gemm(const float* __restrict__ A, const bf16* __restrict__ B2,
               float* __restrict__ C, bf16* __restrict__ outB, bf16* __restrict__ vT,
               int N, int K, int lda, int ldbt, int ldc,
               const float* __restrict__ bias, int vrows,
               const float* __restrict__ gcmem, const float* __restrict__ gmem,
               const float* __restrict__ gx)
{
    int row0 = blockIdx.y * 128, col0 = blockIdx.x * 128;
    int tid = threadIdx.x;

    __shared__ bf16 As[128][72];
    __shared__ bf16 Bs[128][72];

    int r_ = tid >> 3;            // 0..31
    int c4 = (tid & 7) * 4;       // A k-chunk (floats)
    const float* aptr[4];
#pragma unroll
    for (int jj = 0; jj < 4; jj++) {
        int gr = row0 + r_ + 32 * jj;
        if (AMODE == 0) {
            aptr[jj] = A + (long)gr * lda;
        } else {
            int bb = gr / 1152, rr = gr - bb * 1152;
            aptr[jj] = (rr < 128) ? (gcmem + ((long)bb * 128 + rr) * 1024)
                     : (rr < 640) ? (gmem + ((long)bb * 512 + (rr - 128)) * 1024)
                                  : (gx   + ((long)bb * 512 + (rr - 640)) * 1024);
        }
    }
    const bf16* bptr2[2];
    int rn_ = tid >> 2;           // 0..63
    int c8  = (tid & 3) * 8;      // B k-chunk (bf16)
#pragma unroll
    for (int jj = 0; jj < 2; jj++) {
        int gc = col0 + rn_ + 64 * jj;
        bptr2[jj] = (gc < N) ? (B2 + (long)gc * ldbt + c8) : nullptr;
    }

    int lane = tid & 63, wid = tid >> 6;
    int wr = wid >> 1, wc = wid & 1;
    int fr = lane & 15, fq = lane >> 4;

    f32x4 acc[4][4];
#pragma unroll
    for (int i = 0; i < 4; i++)
#pragma unroll
        for (int j = 0; j < 4; j++) acc[i][j] = (f32x4){0.f, 0.f, 0.f, 0.f};

    for (int k0 = 0; k0 < K; k0 += 32) {
#pragma unroll
        for (int jj = 0; jj < 4; jj++) {
            float4 f = *(const float4*)(aptr[jj] + k0 + c4);
            bf16x4 h = { (bf16)f.x, (bf16)f.y, (bf16)f.z, (bf16)f.w };
            *(bf16x4*)&As[r_ + 32 * jj][c4] = h;
        }
#pragma unroll
        for (int jj = 0; jj < 2; jj++) {
            bf16x8 v = {};
            if (bptr2[jj]) v = *(const bf16x8*)(bptr2[jj] + k0);
            *(bf16x8*)&Bs[rn_ + 64 * jj][c8] = v;
        }
        __syncthreads();

        bf16x8 af[4], bfv[4];
#pragma unroll
        for (int i = 0; i < 4; i++)
            af[i] = *(const bf16x8*)&As[wr * 64 + i * 16 + fr][fq * 8];
#pragma unroll
        for (int j = 0; j < 4; j++)
            bfv[j] = *(const bf16x8*)&Bs[wc * 64 + j * 16 + fr][fq * 8];
#pragma unroll
        for (int i = 0; i < 4; i++)
#pragma unroll
            for (int j = 0; j < 4; j++)
                acc[i][j] = __builtin_amdgcn_mfma_f32_16x16x32_bf16(af[i], bfv[j], acc[i][j], 0, 0, 0);
        __syncthreads();
    }

#pragma unroll
    for (int i = 0; i < 4; i++) {
#pragma unroll
        for (int j = 0; j < 4; j++) {
#pragma unroll
            for (int g = 0; g < 4; g++) {
                int r = row0 + wr * 64 + i * 16 + fq * 4 + g;
                int c = col0 + wc * 64 + j * 16 + fr;
                float v = acc[i][j][g];
                if (EPI == 0) {
                    if (c < N) {
                        if (bias) v += bias[c];
                        C[(long)r * ldc + c] = v;
                    }
                } else if (EPI == 6) {
                    if (c < N) {
                        if (bias) v += bias[c];
                        __builtin_nontemporal_store(v, &C[(long)r * ldc + c]);
                    }
                } else if (EPI == 4) {
                    if (c < N) outB[(long)r * ldc + c] = (bf16)v;
                } else { // EPI == 5
                    if (c < 1024) {
                        outB[(long)r * 1024 + c] = (bf16)v;
                    } else {
                        int d = c - 1024; int hh = d >> 6; d &= 63;
                        int bb = r / vrows; int j2 = r - bb * vrows;
                        vT[(((long)(bb * 16 + hh)) * 64 + d) * vrows + j2] = (bf16)v;
                    }
                }
            }
        }
    }
}

// fp32 [R][C] -> bf16 [C][R]
__global__ __launch_bounds__(256)
void transpose_cast(const float* __restrict__ in, bf16* __restrict__ out, int R, int C)
{
    __shared__ float t[32][33];
    int c0 = blockIdx.x * 32, r0 = blockIdx.y * 32;
    int tx = threadIdx.x & 31, ty = threadIdx.x >> 5;
#pragma unroll
    for (int i = 0; i < 32; i += 8)
        t[ty + i][tx] = in[(long)(r0 + ty + i) * C + c0 + tx];
    __syncthreads();
#pragma unroll
    for (int i = 0; i < 32; i += 8)
        out[(long)(c0 + ty + i) * R + r0 + tx] = (bf16)t[tx][ty + i];
}

// conv_w [o][i][r] -> bf16 [o][r*1024+i]
__global__ __launch_bounds__(256)
void convw_cast(const float* __restrict__ cw, bf16* __restrict__ out)
{
    long o = blockIdx.x;
    const float* src = cw + o * 4096;
    bf16* dst = out + o * 4096;
    for (int d = threadIdx.x; d < 4096; d += 256)
        dst[d] = (bf16)src[((d & 1023) << 2) | (d >> 10)];
}

// elementwise fp32 -> bf16 (vectorized by 4)
__global__ __launch_bounds__(256)
void cast_f2b(const float* __restrict__ in, bf16* __restrict__ out, int n4)
{
    int i = blockIdx.x * 256 + threadIdx.x;
    int stride = gridDim.x * 256;
    for (; i < n4; i += stride) {
        float4 f = reinterpret_cast<const float4*>(in)[i];
        bf16x4 h = { (bf16)f.x, (bf16)f.y, (bf16)f.z, (bf16)f.w };
        reinterpret_cast<bf16x4*>(out)[i] = h;
    }
}

// ---------------------------------------------------------------------------
// Fused attention, 16 q-rows per block, 4 waves. Barrier-free S-build:
// each wave computes its own pe-band tiles (private pband slice) and its own
// qk columns. 2 barriers total per block. weights stored non-temporally.
// ---------------------------------------------------------------------------
#define SSTR 1164

__global__ __launch_bounds__(256)
void attn_fused16(const bf16* __restrict__ qb, const bf16* __restrict__ kb,
                  const bf16* __restrict__ peb, const bf16* __restrict__ vTb,
                  float* __restrict__ weights, float* __restrict__ oat)
{
    int z = blockIdx.y;              // b*16 + h
    int b = z >> 4, h = z & 15;
    int r0 = blockIdx.x * 16;
    int tid = threadIdx.x;
    int lane = tid & 63, wid = tid >> 6;
    int fr = lane & 15, fq = lane >> 4;

    __shared__ bf16 S[16 * SSTR];      // 36.4 KB
    __shared__ bf16 pband[4][16][56];  // per-wave private band, 7 KB

    // q fragments direct from global
    bf16x8 afr[2];
#pragma unroll
    for (int ks = 0; ks < 2; ks++)
        afr[ks] = *(const bf16x8*)&qb[((long)(b * 512 + r0 + fr)) * 1024 + h * 64 + ks * 32 + fq * 8];

    // ---------------- S build: 9 chunks, no cross-wave sync ----------------
#pragma unroll 3
    for (int ch = 0; ch < 9; ch++) {
        int c0 = ch * 128;
        int jb0 = c0 + 496 - r0 + 32 * wid;   // wave-local band start

        // 3 pos tiles covering band cols [32w, 32w+48)
#pragma unroll
        for (int ct = 0; ct < 3; ct++) {
            f32x4 a = (f32x4){0.f, 0.f, 0.f, 0.f};
            int j = jb0 + ct * 16 + fr;
            bool ok = (j < 1152);
#pragma unroll
            for (int ks = 0; ks < 2; ks++) {
                bf16x8 bv = {};
                if (ok) bv = *(const bf16x8*)&peb[((long)(h * 1152 + j)) * 64 + ks * 32 + fq * 8];
                a = __builtin_amdgcn_mfma_f32_16x16x32_bf16(afr[ks], bv, a, 0, 0, 0);
            }
#pragma unroll
            for (int g = 0; g < 4; g++) pband[wid][fq * 4 + g][ct * 16 + fr] = (bf16)a[g];
        }

        // 2 qk tiles (cols c0+32w .. c0+32w+32), read own pband slice
#pragma unroll
        for (int tt = 0; tt < 2; tt++) {
            int cc = 32 * wid + 16 * tt + fr;
            f32x4 a = (f32x4){0.f, 0.f, 0.f, 0.f};
            long krow = (long)(b * 1152 + c0 + cc);
#pragma unroll
            for (int ks = 0; ks < 2; ks++) {
                bf16x8 bv = *(const bf16x8*)&kb[krow * 1024 + h * 64 + ks * 32 + fq * 8];
                a = __builtin_amdgcn_mfma_f32_16x16x32_bf16(afr[ks], bv, a, 0, 0, 0);
            }
#pragma unroll
            for (int g = 0; g < 4; g++) {
                int rr = fq * 4 + g;
                S[rr * SSTR + c0 + cc] =
                    (bf16)(0.125f * (a[g] + (float)pband[wid][rr][16 * tt + (fr + 15 - rr)]));
            }
        }
    }
    __syncthreads();

    // ---------------- softmax: 4 waves x 4 rows ----------------
    for (int rw = 0; rw < 4; rw++) {
        int row = wid * 4 + rw;
        float ebuf[18];
        float m = -3.4e38f;
#pragma unroll
        for (int k = 0; k < 18; k++) {
            float v = (float)S[row * SSTR + lane + 64 * k];
            ebuf[k] = v; m = fmaxf(m, v);
        }
#pragma unroll
        for (int off = 32; off; off >>= 1) m = fmaxf(m, __shfl_xor(m, off, 64));
        float sm = 0.f;
#pragma unroll
        for (int k = 0; k < 18; k++) { float e = __expf(ebuf[k] - m); ebuf[k] = e; sm += e; }
#pragma unroll
        for (int off = 32; off; off >>= 1) sm += __shfl_xor(sm, off, 64);
        float inv = 1.f / sm;
        long wbase = ((long)z * 512 + r0 + row) * 1152 + lane;
#pragma unroll
        for (int k = 0; k < 18; k++) {
            float p = ebuf[k] * inv;
            __builtin_nontemporal_store(p, &weights[wbase + 64 * k]);
            S[row * SSTR + lane + 64 * k] = (bf16)p;
        }
    }
    __syncthreads();

    // ---------------- PV: wave wid owns d-tile dt=wid ----------------
    f32x4 oacc = (f32x4){0.f, 0.f, 0.f, 0.f};
    int dt = wid;
    for (int ch = 0; ch < 9; ch++) {
        int c0 = ch * 128;
#pragma unroll
        for (int ks = 0; ks < 4; ks++) {
            bf16x8 pa = *(const bf16x8*)&S[fr * SSTR + c0 + ks * 32 + fq * 8];
            bf16x8 vb = *(const bf16x8*)&vTb[((long)z * 64 + dt * 16 + fr) * 1152 + c0 + ks * 32 + fq * 8];
            oacc = __builtin_amdgcn_mfma_f32_16x16x32_bf16(pa, vb, oacc, 0, 0, 0);
        }
    }
#pragma unroll
    for (int g = 0; g < 4; g++)
        oat[((long)(b * 512 + r0 + fq * 4 + g)) * 1024 + h * 64 + dt * 16 + fr] = oacc[g];
}

// ---------------------------------------------------------------------------
// Fused MFMA aux loss (bf16-staged sources)
// ---------------------------------------------------------------------------
__global__ __launch_bounds__(256)
void aux_mfma_kernel(const bf16* __restrict__ qb, const bf16* __restrict__ kb,
                     const bf16* __restrict__ ckb,
                     const bf16* __restrict__ vTb, const bf16* __restrict__ cvT,
                     float* __restrict__ partials)
{
    int z = blockIdx.y;
    int b = z >> 4, h = z & 15;
    int r0 = blockIdx.x * 128;
    int tid = threadIdx.x;
    int lane = tid & 63, wid = tid >> 6;
    int fr = lane & 15, fq = lane >> 4;

    __shared__ bf16 qs[128][72];
    __shared__ bf16 upool[128 * 136];
    __shared__ bf16 vt[64][136];
    __shared__ float wred[4];

#pragma unroll
    for (int t = 0; t < 4; t++) {
        int e = tid + 256 * t; int rr = e >> 3, c8 = (e & 7) * 8;
        *(bf16x8*)&qs[rr][c8] = *(const bf16x8*)&qb[((long)(b * 512 + r0 + rr)) * 1024 + h * 64 + c8];
    }

    float o1[2][4][4];
    f32x4 oaccv[2][4];
    float mrow[2][4], lrow[2][4];
    f32x4 sacc[2][8];
    float local = 0.f;

    for (int pass = 0; pass < 2; pass++) {
#pragma unroll
        for (int i = 0; i < 2; i++)
#pragma unroll
            for (int g = 0; g < 4; g++) { mrow[i][g] = -3.4e38f; lrow[i][g] = 0.f; }
#pragma unroll
        for (int i = 0; i < 2; i++)
#pragma unroll
            for (int jd = 0; jd < 4; jd++) oaccv[i][jd] = (f32x4){0.f, 0.f, 0.f, 0.f};

        int nchunk = pass ? 1 : 4;
        for (int jt = 0; jt < nchunk; jt++) {
            __syncthreads();
            if (pass == 0) {
                long base = (long)(b * 1152 + 128 + jt * 128);
#pragma unroll
                for (int t = 0; t < 4; t++) {
                    int e = tid + 256 * t; int j = e >> 3, c8 = (e & 7) * 8;
                    *(bf16x8*)&upool[j * 72 + c8] = *(const bf16x8*)&kb[(base + j) * 1024 + h * 64 + c8];
                }
#pragma unroll
                for (int t = 0; t < 4; t++) {
                    int e = tid + 256 * t; int d = e >> 4, j8 = (e & 15) * 8;
                    *(bf16x8*)&vt[d][j8] =
                        *(const bf16x8*)&vTb[((long)z * 64 + d) * 1152 + 128 + jt * 128 + j8];
                }
            } else {
#pragma unroll
                for (int t = 0; t < 4; t++) {
                    int e = tid + 256 * t; int j = e >> 3, c8 = (e & 7) * 8;
                    *(bf16x8*)&upool[j * 72 + c8] = *(const bf16x8*)&ckb[((long)(b * 128 + j)) * 1024 + h * 64 + c8];
                }
#pragma unroll
                for (int t = 0; t < 4; t++) {
                    int e = tid + 256 * t; int d = e >> 4, j8 = (e & 15) * 8;
                    *(bf16x8*)&vt[d][j8] = *(const bf16x8*)&cvT[((long)z * 64 + d) * 128 + j8];
                }
            }
            __syncthreads();

#pragma unroll
            for (int i = 0; i < 2; i++)
#pragma unroll
                for (int j = 0; j < 8; j++) sacc[i][j] = (f32x4){0.f, 0.f, 0.f, 0.f};
#pragma unroll
            for (int s = 0; s < 2; s++) {
                bf16x8 af[2], bfv[8];
#pragma unroll
                for (int i = 0; i < 2; i++)
                    af[i] = *(const bf16x8*)&qs[wid * 32 + i * 16 + fr][s * 32 + fq * 8];
#pragma unroll
                for (int j = 0; j < 8; j++)
                    bfv[j] = *(const bf16x8*)&upool[(j * 16 + fr) * 72 + s * 32 + fq * 8];
#pragma unroll
                for (int i = 0; i < 2; i++)
#pragma unroll
                    for (int j = 0; j < 8; j++)
                        sacc[i][j] = __builtin_amdgcn_mfma_f32_16x16x32_bf16(af[i], bfv[j], sacc[i][j], 0, 0, 0);
            }
            __syncthreads();

#pragma unroll
            for (int i = 0; i < 2; i++) {
#pragma unroll
                for (int g = 0; g < 4; g++) {
                    float mx = -3.4e38f;
#pragma unroll
                    for (int j = 0; j < 8; j++) mx = fmaxf(mx, sacc[i][j][g]);
                    mx *= 0.125f;
#pragma unroll
                    for (int msk = 1; msk <= 8; msk <<= 1) mx = fmaxf(mx, __shfl_xor(mx, msk, 64));
                    float mnew = fmaxf(mrow[i][g], mx);
                    float alpha = __expf(mrow[i][g] - mnew);
                    mrow[i][g] = mnew;
                    float sum = 0.f;
                    int prow = (wid * 32 + i * 16 + fq * 4 + g) * 136;
#pragma unroll
                    for (int j = 0; j < 8; j++) {
                        float p = __expf(sacc[i][j][g] * 0.125f - mnew);
                        sum += p;
                        upool[prow + j * 16 + fr] = (bf16)p;
                    }
#pragma unroll
                    for (int msk = 1; msk <= 8; msk <<= 1) sum += __shfl_xor(sum, msk, 16);
                    lrow[i][g] = lrow[i][g] * alpha + sum;
#pragma unroll
                    for (int jd = 0; jd < 4; jd++) oaccv[i][jd][g] *= alpha;
                }
            }
            __syncthreads();

#pragma unroll
            for (int s2 = 0; s2 < 4; s2++) {
                bf16x8 pa[2], vb[4];
#pragma unroll
                for (int i = 0; i < 2; i++)
                    pa[i] = *(const bf16x8*)&upool[(wid * 32 + i * 16 + fr) * 136 + s2 * 32 + fq * 8];
#pragma unroll
                for (int jd = 0; jd < 4; jd++)
                    vb[jd] = *(const bf16x8*)&vt[jd * 16 + fr][s2 * 32 + fq * 8];
#pragma unroll
                for (int i = 0; i < 2; i++)
#pragma unroll
                    for (int jd = 0; jd < 4; jd++)
                        oaccv[i][jd] = __builtin_amdgcn_mfma_f32_16x16x32_bf16(pa[i], vb[jd], oaccv[i][jd], 0, 0, 0);
            }
        }

        if (pass == 0) {
#pragma unroll
            for (int i = 0; i < 2; i++)
#pragma unroll
                for (int jd = 0; jd < 4; jd++)
#pragma unroll
                    for (int g = 0; g < 4; g++)
                        o1[i][jd][g] = oaccv[i][jd][g] / lrow[i][g];
        } else {
#pragma unroll
            for (int i = 0; i < 2; i++)
#pragma unroll
                for (int jd = 0; jd < 4; jd++)
#pragma unroll
                    for (int g = 0; g < 4; g++) {
                        float dd = o1[i][jd][g] - oaccv[i][jd][g] / lrow[i][g];
                        local += dd * dd;
                    }
        }
    }

#pragma unroll
    for (int off = 32; off; off >>= 1) local += __shfl_xor(local, off, 64);
    if (lane == 0) wred[wid] = local;
    __syncthreads();
    if (tid == 0)
        partials[(long)blockIdx.y * 4 + blockIdx.x] = wred[0] + wred[1] + wred[2] + wred[3];
}

__global__ __launch_bounds__(256)
void aux_reduce_kernel(const float* __restrict__ partials, float* __restrict__ out)
{
    int tid = threadIdx.x;
    __shared__ float wred[4];
    float s = 0.f;
    for (int i = tid; i < 512; i += 256) s += partials[i];
#pragma unroll
    for (int off = 32; off; off >>= 1) s += __shfl_xor(s, off, 64);
    if ((tid & 63) == 0) wred[tid >> 6] = s;
    __syncthreads();
    if (tid == 0) out[0] = (wred[0] + wred[1] + wred[2] + wred[3]) * (1.0f / 4194304.0f);
}

__global__ __launch_bounds__(256)
void copy_kernel(float* __restrict__ dst, const float* __restrict__ src, int n4)
{
    int i = blockIdx.x * 256 + threadIdx.x;
    int stride = gridDim.x * 256;
    for (; i < n4; i += stride) {
        f32x4 v = reinterpret_cast<const f32x4*>(src)[i];
        __builtin_nontemporal_store(v, &reinterpret_cast<f32x4*>(dst)[i]);
    }
}

extern "C" void kernel_launch(void* const* d_in, const int* in_sizes, int n_in,
                              void* d_out, int out_size, void* d_ws, size_t ws_size,
                              hipStream_t stream)
{
    const float* x      = (const float*)d_in[0];
    const float* mem    = (const float*)d_in[1];
    const float* cmem   = (const float*)d_in[2];
    const float* pe     = (const float*)d_in[3];
    const float* Wq     = (const float*)d_in[4];
    const float* Wkv    = (const float*)d_in[5];
    const float* Wout   = (const float*)d_in[6];
    const float* bout   = (const float*)d_in[7];
    const float* conv_w = (const float*)d_in[8];
    const float* conv_b = (const float*)d_in[9];

    float* out_logits  = (float*)d_out;                 // 8*512*1024
    float* out_newmem  = out_logits + 4194304;          // 8*512*1024
    float* out_newcmem = out_newmem + 4194304;          // 8*128*1024
    float* out_aux     = out_newcmem + 1048576;         // 1
    float* out_weights = out_aux + 1;                   // 8*16*512*1152

    float* ws       = (float*)d_ws;
    float* oat      = ws;                    // 4,194,304 f
    float* partials = oat + 4194304;         // 4096 f
    bf16* bws     = (bf16*)(partials + 4096);
    bf16* WqTb    = bws;                     // 1,048,576
    bf16* WkvTb   = WqTb + 1048576;          // 2,097,152
    bf16* WoutTb  = WkvTb + 2097152;         // 1,048,576
    bf16* convwTb = WoutTb + 1048576;        // 4,194,304
    bf16* vTb     = convwTb + 4194304;       // 9,437,184
    bf16* cvT     = vTb + 9437184;           // 1,048,576
    bf16* qb      = cvT + 1048576;           // 4,194,304
    bf16* kb      = qb + 4194304;            // 9,437,184
    bf16* ckb     = kb + 9437184;            // 1,048,576
    bf16* peb     = ckb + 1048576;           // 1,179,648

    dim3 blk(256);

    transpose_cast<<<dim3(32, 32), blk, 0, stream>>>(Wq, WqTb, 1024, 1024);
    transpose_cast<<<dim3(64, 32), blk, 0, stream>>>(Wkv, WkvTb, 1024, 2048);
    transpose_cast<<<dim3(32, 32), blk, 0, stream>>>(Wout, WoutTb, 1024, 1024);
    convw_cast<<<dim3(1024), blk, 0, stream>>>(conv_w, convwTb);
    cast_f2b<<<dim3(1152), blk, 0, stream>>>(pe, peb, 294912);

    // qb = bf16(x @ Wq)
    mfma_gemm<0, 4><<<dim3(8, 32, 1), blk, 0, stream>>>(
        x, WqTb, nullptr, qb, nullptr, 1024, 1024, 1024, 1024, 1024,
        nullptr, 0, nullptr, nullptr, nullptr);

    // kb/vTb = bf16(concat(cmem,mem,x) @ Wkv)
    mfma_gemm<1, 5><<<dim3(16, 72, 1), blk, 0, stream>>>(
        nullptr, WkvTb, nullptr, kb, vTb, 2048, 1024, 1024, 1024, 2048,
        nullptr, 1152, cmem, mem, x);

    // new_cmem = mem[1024x4096] @ convwT + conv_b (fp32 output, re-read by ckv)
    mfma_gemm<0, 0><<<dim3(8, 8, 1), blk, 0, stream>>>(
        mem, convwTb, out_newcmem, nullptr, nullptr, 1024, 4096, 4096, 4096, 1024,
        conv_b, 0, nullptr, nullptr, nullptr);

    // ckb/cvT = bf16(new_cmem @ Wkv)
    mfma_gemm<0, 5><<<dim3(16, 8, 1), blk, 0, stream>>>(
        out_newcmem, WkvTb, nullptr, ckb, cvT, 2048, 1024, 1024, 1024, 2048,
        nullptr, 128, nullptr, nullptr, nullptr);

    // fused attention: dots(+pos shift) -> softmax -> weights + oat
    attn_fused16<<<dim3(32, 128), blk, 0, stream>>>(qb, kb, peb, vTb, out_weights, oat);

    // logits = oat @ Wout + bout (non-temporal output)
    mfma_gemm<0, 6><<<dim3(8, 32, 1), blk, 0, stream>>>(
        oat, WoutTb, out_logits, nullptr, nullptr, 1024, 1024, 1024, 1024, 1024,
        bout, 0, nullptr, nullptr, nullptr);

    // new_mem = x (non-temporal)
    copy_kernel<<<dim3(4096), blk, 0, stream>>>(out_newmem, x, 1048576);

    // aux loss
    aux_mfma_kernel<<<dim3(4, 128), blk, 0, stream>>>(qb, kb, ckb, vTb, cvT, partials);
    aux_reduce_kernel<<<dim3(1), blk, 0, stream>>>(partials, out_aux);
}

// Round 8
// 690.836 us; speedup vs baseline: 2.2553x; 1.3688x over previous
//
#include <hip/hip_runtime.h>
#include <cstdint>

// HEADS=16, DIM=1024, SEQ=512, MEM=512, CMEM=128, RATIO=4, DIM_H=64, b=8, kv_len=1152

typedef __bf16 bf16;
typedef __bf16 bf16x4 __attribute__((ext_vector_type(4)));
typedef __bf16 bf16x8 __attribute__((ext_vector_type(8)));
typedef float  f32x4  __attribute__((ext_vector_type(4)));

// ---------------------------------------------------------------------------
// MFMA GEMM: C[M,N] = A[M,K] @ B[K,N], tile 128x128, BK=32, 4 waves.
// A: bf16 row-major (AMODE0) or concat-gather rows of cmemb/memb/xb (AMODE1).
// B: bf16 BT layout [N][K].
// EPI 0: fp32 C (+bias)
// EPI 4: bf16-only output: outB[r*ldc + c]
// EPI 5: bf16 outB[r*1024+c] for c<1024, bf16 vT for c>=1024 (row mod vrows)
// EPI 6: fp32 C (+bias), non-temporal store
// EPI 7: fp32 C (+bias) AND bf16 outB[r*1024+c]
// ---------------------------------------------------------------------------
template<int AMODE, int EPI>
__global__ __launch_bounds__(256)
void mfma_gemm(const bf16* __restrict__ A, const bf16* __restrict__ B2,
               float* __restrict__ C, bf16* __restrict__ outB, bf16* __restrict__ vT,
               int N, int K, int lda, int ldbt, int ldc,
               const float* __restrict__ bias, int vrows,
               const bf16* __restrict__ gcmem, const bf16* __restrict__ gmem,
               const bf16* __restrict__ gx)
{
    int row0 = blockIdx.y * 128, col0 = blockIdx.x * 128;
    int tid = threadIdx.x;

    __shared__ bf16 As[128][72];
    __shared__ bf16 Bs[128][72];

    int rn_ = tid >> 2;           // 0..63
    int c8  = (tid & 3) * 8;      // k-chunk (bf16)

    const bf16* aptr[2];
#pragma unroll
    for (int jj = 0; jj < 2; jj++) {
        int gr = row0 + rn_ + 64 * jj;
        if (AMODE == 0) {
            aptr[jj] = A + (long)gr * lda;
        } else {
            int bb = gr / 1152, rr = gr - bb * 1152;
            aptr[jj] = (rr < 128) ? (gcmem + ((long)bb * 128 + rr) * 1024)
                     : (rr < 640) ? (gmem + ((long)bb * 512 + (rr - 128)) * 1024)
                                  : (gx   + ((long)bb * 512 + (rr - 640)) * 1024);
        }
    }
    const bf16* bptr[2];
#pragma unroll
    for (int jj = 0; jj < 2; jj++) {
        int gc = col0 + rn_ + 64 * jj;
        bptr[jj] = (gc < N) ? (B2 + (long)gc * ldbt + c8) : nullptr;
    }

    int lane = tid & 63, wid = tid >> 6;
    int wr = wid >> 1, wc = wid & 1;
    int fr = lane & 15, fq = lane >> 4;

    f32x4 acc[4][4];
#pragma unroll
    for (int i = 0; i < 4; i++)
#pragma unroll
        for (int j = 0; j < 4; j++) acc[i][j] = (f32x4){0.f, 0.f, 0.f, 0.f};

    for (int k0 = 0; k0 < K; k0 += 32) {
#pragma unroll
        for (int jj = 0; jj < 2; jj++) {
            bf16x8 v = *(const bf16x8*)(aptr[jj] + k0 + c8);
            *(bf16x8*)&As[rn_ + 64 * jj][c8] = v;
        }
#pragma unroll
        for (int jj = 0; jj < 2; jj++) {
            bf16x8 v = {};
            if (bptr[jj]) v = *(const bf16x8*)(bptr[jj] + k0);
            *(bf16x8*)&Bs[rn_ + 64 * jj][c8] = v;
        }
        __syncthreads();

        bf16x8 af[4], bfv[4];
#pragma unroll
        for (int i = 0; i < 4; i++)
            af[i] = *(const bf16x8*)&As[wr * 64 + i * 16 + fr][fq * 8];
#pragma unroll
        for (int j = 0; j < 4; j++)
            bfv[j] = *(const bf16x8*)&Bs[wc * 64 + j * 16 + fr][fq * 8];
#pragma unroll
        for (int i = 0; i < 4; i++)
#pragma unroll
            for (int j = 0; j < 4; j++)
                acc[i][j] = __builtin_amdgcn_mfma_f32_16x16x32_bf16(af[i], bfv[j], acc[i][j], 0, 0, 0);
        __syncthreads();
    }

#pragma unroll
    for (int i = 0; i < 4; i++) {
#pragma unroll
        for (int j = 0; j < 4; j++) {
#pragma unroll
            for (int g = 0; g < 4; g++) {
                int r = row0 + wr * 64 + i * 16 + fq * 4 + g;
                int c = col0 + wc * 64 + j * 16 + fr;
                float v = acc[i][j][g];
                if (EPI == 0) {
                    if (c < N) {
                        if (bias) v += bias[c];
                        C[(long)r * ldc + c] = v;
                    }
                } else if (EPI == 6) {
                    if (c < N) {
                        if (bias) v += bias[c];
                        __builtin_nontemporal_store(v, &C[(long)r * ldc + c]);
                    }
                } else if (EPI == 7) {
                    if (c < N) {
                        if (bias) v += bias[c];
                        C[(long)r * ldc + c] = v;
                        outB[(long)r * 1024 + c] = (bf16)v;
                    }
                } else if (EPI == 4) {
                    if (c < N) outB[(long)r * ldc + c] = (bf16)v;
                } else { // EPI == 5
                    if (c < 1024) {
                        outB[(long)r * 1024 + c] = (bf16)v;
                    } else {
                        int d = c - 1024; int hh = d >> 6; d &= 63;
                        int bb = r / vrows; int j2 = r - bb * vrows;
                        vT[(((long)(bb * 16 + hh)) * 64 + d) * vrows + j2] = (bf16)v;
                    }
                }
            }
        }
    }
}

// fp32 [R][C] -> bf16 [C][R]
__global__ __launch_bounds__(256)
void transpose_cast(const float* __restrict__ in, bf16* __restrict__ out, int R, int C)
{
    __shared__ float t[32][33];
    int c0 = blockIdx.x * 32, r0 = blockIdx.y * 32;
    int tx = threadIdx.x & 31, ty = threadIdx.x >> 5;
#pragma unroll
    for (int i = 0; i < 32; i += 8)
        t[ty + i][tx] = in[(long)(r0 + ty + i) * C + c0 + tx];
    __syncthreads();
#pragma unroll
    for (int i = 0; i < 32; i += 8)
        out[(long)(c0 + ty + i) * R + r0 + tx] = (bf16)t[tx][ty + i];
}

// conv_w [o][i][r] -> bf16 [o][r*1024+i]
__global__ __launch_bounds__(256)
void convw_cast(const float* __restrict__ cw, bf16* __restrict__ out)
{
    long o = blockIdx.x;
    const float* src = cw + o * 4096;
    bf16* dst = out + o * 4096;
    for (int d = threadIdx.x; d < 4096; d += 256)
        dst[d] = (bf16)src[((d & 1023) << 2) | (d >> 10)];
}

// elementwise fp32 -> bf16 (vectorized by 4)
__global__ __launch_bounds__(256)
void cast_f2b(const float* __restrict__ in, bf16* __restrict__ out, int n4)
{
    int i = blockIdx.x * 256 + threadIdx.x;
    int stride = gridDim.x * 256;
    for (; i < n4; i += stride) {
        float4 f = reinterpret_cast<const float4*>(in)[i];
        bf16x4 h = { (bf16)f.x, (bf16)f.y, (bf16)f.z, (bf16)f.w };
        reinterpret_cast<bf16x4*>(out)[i] = h;
    }
}

// ---------------------------------------------------------------------------
// Fused attention, 16 q-rows per block, 4 waves. S-build with in-register
// shifted-pos (shuffle) -- no pband LDS. LDS = S only (37.2KB, 4 blocks/CU).
// ---------------------------------------------------------------------------
#define SSTR 1164

__global__ __launch_bounds__(256)
void attn_fused16(const bf16* __restrict__ qb, const bf16* __restrict__ kb,
                  const bf16* __restrict__ peb, const bf16* __restrict__ vTb,
                  float* __restrict__ weights, bf16* __restrict__ oatb)
{
    int z = blockIdx.y;              // b*16 + h
    int b = z >> 4, h = z & 15;
    int r0 = blockIdx.x * 16;
    int tid = threadIdx.x;
    int lane = tid & 63, wid = tid >> 6;
    int fr = lane & 15, fq = lane >> 4;

    __shared__ bf16 S[16 * SSTR];      // 37.2 KB

    // q fragments direct from global
    bf16x8 afr[2];
#pragma unroll
    for (int ks = 0; ks < 2; ks++)
        afr[ks] = *(const bf16x8*)&qb[((long)(b * 512 + r0 + fr)) * 1024 + h * 64 + ks * 32 + fq * 8];

    // ---------------- S build: 9 chunks, no cross-wave sync ----------------
#pragma unroll 3
    for (int ch = 0; ch < 9; ch++) {
        int c0 = ch * 128;
        int jb0 = c0 + 496 - r0 + 32 * wid;   // wave-local band start

        // 3 pos tiles (band cols [32w, 32w+48)) -> register fragments
        f32x4 p[3];
#pragma unroll
        for (int ct = 0; ct < 3; ct++) {
            f32x4 a = (f32x4){0.f, 0.f, 0.f, 0.f};
            int j = jb0 + ct * 16 + fr;
            bool ok = (j < 1152);
#pragma unroll
            for (int ks = 0; ks < 2; ks++) {
                bf16x8 bv = {};
                if (ok) bv = *(const bf16x8*)&peb[((long)(h * 1152 + j)) * 64 + ks * 32 + fq * 8];
                a = __builtin_amdgcn_mfma_f32_16x16x32_bf16(afr[ks], bv, a, 0, 0, 0);
            }
            p[ct] = a;
        }

        // 2 qk tiles; shifted pos via cross-lane shuffle from p[] fragments
#pragma unroll
        for (int tt = 0; tt < 2; tt++) {
            int cc = 32 * wid + 16 * tt + fr;
            f32x4 a = (f32x4){0.f, 0.f, 0.f, 0.f};
            long krow = (long)(b * 1152 + c0 + cc);
#pragma unroll
            for (int ks = 0; ks < 2; ks++) {
                bf16x8 bv = *(const bf16x8*)&kb[krow * 1024 + h * 64 + ks * 32 + fq * 8];
                a = __builtin_amdgcn_mfma_f32_16x16x32_bf16(afr[ks], bv, a, 0, 0, 0);
            }
#pragma unroll
            for (int g = 0; g < 4; g++) {
                int rr = fq * 4 + g;
                int uu = fr + 15 - rr;                 // 0..30
                int src = (uu & 15) | (fq << 4);
                // P[rr][16*tt+uu] lives in lane src, reg g of band tile tt+(uu>>4)
                float s0 = __shfl(p[tt][g], src, 64);
                float s1 = __shfl(p[tt + 1][g], src, 64);
                float pv = (uu < 16) ? s0 : s1;
                S[rr * SSTR + c0 + cc] = (bf16)(0.125f * (a[g] + pv));
            }
        }
    }
    __syncthreads();

    // ---------------- softmax: 4 waves x 4 rows ----------------
    for (int rw = 0; rw < 4; rw++) {
        int row = wid * 4 + rw;
        float ebuf[18];
        float m = -3.4e38f;
#pragma unroll
        for (int k = 0; k < 18; k++) {
            float v = (float)S[row * SSTR + lane + 64 * k];
            ebuf[k] = v; m = fmaxf(m, v);
        }
#pragma unroll
        for (int off = 32; off; off >>= 1) m = fmaxf(m, __shfl_xor(m, off, 64));
        float sm = 0.f;
#pragma unroll
        for (int k = 0; k < 18; k++) { float e = __expf(ebuf[k] - m); ebuf[k] = e; sm += e; }
#pragma unroll
        for (int off = 32; off; off >>= 1) sm += __shfl_xor(sm, off, 64);
        float inv = 1.f / sm;
        long wbase = ((long)z * 512 + r0 + row) * 1152 + lane;
#pragma unroll
        for (int k = 0; k < 18; k++) {
            float pv = ebuf[k] * inv;
            __builtin_nontemporal_store(pv, &weights[wbase + 64 * k]);
            S[row * SSTR + lane + 64 * k] = (bf16)pv;
        }
    }
    __syncthreads();

    // ---------------- PV: wave wid owns d-tile dt=wid; output bf16 ----------------
    f32x4 oacc = (f32x4){0.f, 0.f, 0.f, 0.f};
    int dt = wid;
    for (int ch = 0; ch < 9; ch++) {
        int c0 = ch * 128;
#pragma unroll
        for (int ks = 0; ks < 4; ks++) {
            bf16x8 pa = *(const bf16x8*)&S[fr * SSTR + c0 + ks * 32 + fq * 8];
            bf16x8 vb = *(const bf16x8*)&vTb[((long)z * 64 + dt * 16 + fr) * 1152 + c0 + ks * 32 + fq * 8];
            oacc = __builtin_amdgcn_mfma_f32_16x16x32_bf16(pa, vb, oacc, 0, 0, 0);
        }
    }
#pragma unroll
    for (int g = 0; g < 4; g++)
        oatb[((long)(b * 512 + r0 + fq * 4 + g)) * 1024 + h * 64 + dt * 16 + fr] = (bf16)oacc[g];
}

// ---------------------------------------------------------------------------
// Fused MFMA aux loss (bf16-staged sources)
// ---------------------------------------------------------------------------
__global__ __launch_bounds__(256)
void aux_mfma_kernel(const bf16* __restrict__ qb, const bf16* __restrict__ kb,
                     const bf16* __restrict__ ckb,
                     const bf16* __restrict__ vTb, const bf16* __restrict__ cvT,
                     float* __restrict__ partials)
{
    int z = blockIdx.y;
    int b = z >> 4, h = z & 15;
    int r0 = blockIdx.x * 128;
    int tid = threadIdx.x;
    int lane = tid & 63, wid = tid >> 6;
    int fr = lane & 15, fq = lane >> 4;

    __shared__ bf16 qs[128][72];
    __shared__ bf16 upool[128 * 136];
    __shared__ bf16 vt[64][136];
    __shared__ float wred[4];

#pragma unroll
    for (int t = 0; t < 4; t++) {
        int e = tid + 256 * t; int rr = e >> 3, c8 = (e & 7) * 8;
        *(bf16x8*)&qs[rr][c8] = *(const bf16x8*)&qb[((long)(b * 512 + r0 + rr)) * 1024 + h * 64 + c8];
    }

    float o1[2][4][4];
    f32x4 oaccv[2][4];
    float mrow[2][4], lrow[2][4];
    f32x4 sacc[2][8];
    float local = 0.f;

    for (int pass = 0; pass < 2; pass++) {
#pragma unroll
        for (int i = 0; i < 2; i++)
#pragma unroll
            for (int g = 0; g < 4; g++) { mrow[i][g] = -3.4e38f; lrow[i][g] = 0.f; }
#pragma unroll
        for (int i = 0; i < 2; i++)
#pragma unroll
            for (int jd = 0; jd < 4; jd++) oaccv[i][jd] = (f32x4){0.f, 0.f, 0.f, 0.f};

        int nchunk = pass ? 1 : 4;
        for (int jt = 0; jt < nchunk; jt++) {
            __syncthreads();
            if (pass == 0) {
                long base = (long)(b * 1152 + 128 + jt * 128);
#pragma unroll
                for (int t = 0; t < 4; t++) {
                    int e = tid + 256 * t; int j = e >> 3, c8 = (e & 7) * 8;
                    *(bf16x8*)&upool[j * 72 + c8] = *(const bf16x8*)&kb[(base + j) * 1024 + h * 64 + c8];
                }
#pragma unroll
                for (int t = 0; t < 4; t++) {
                    int e = tid + 256 * t; int d = e >> 4, j8 = (e & 15) * 8;
                    *(bf16x8*)&vt[d][j8] =
                        *(const bf16x8*)&vTb[((long)z * 64 + d) * 1152 + 128 + jt * 128 + j8];
                }
            } else {
#pragma unroll
                for (int t = 0; t < 4; t++) {
                    int e = tid + 256 * t; int j = e >> 3, c8 = (e & 7) * 8;
                    *(bf16x8*)&upool[j * 72 + c8] = *(const bf16x8*)&ckb[((long)(b * 128 + j)) * 1024 + h * 64 + c8];
                }
#pragma unroll
                for (int t = 0; t < 4; t++) {
                    int e = tid + 256 * t; int d = e >> 4, j8 = (e & 15) * 8;
                    *(bf16x8*)&vt[d][j8] = *(const bf16x8*)&cvT[((long)z * 64 + d) * 128 + j8];
                }
            }
            __syncthreads();

#pragma unroll
            for (int i = 0; i < 2; i++)
#pragma unroll
                for (int j = 0; j < 8; j++) sacc[i][j] = (f32x4){0.f, 0.f, 0.f, 0.f};
#pragma unroll
            for (int s = 0; s < 2; s++) {
                bf16x8 af[2], bfv[8];
#pragma unroll
                for (int i = 0; i < 2; i++)
                    af[i] = *(const bf16x8*)&qs[wid * 32 + i * 16 + fr][s * 32 + fq * 8];
#pragma unroll
                for (int j = 0; j < 8; j++)
                    bfv[j] = *(const bf16x8*)&upool[(j * 16 + fr) * 72 + s * 32 + fq * 8];
#pragma unroll
                for (int i = 0; i < 2; i++)
#pragma unroll
                    for (int j = 0; j < 8; j++)
                        sacc[i][j] = __builtin_amdgcn_mfma_f32_16x16x32_bf16(af[i], bfv[j], sacc[i][j], 0, 0, 0);
            }
            __syncthreads();

#pragma unroll
            for (int i = 0; i < 2; i++) {
#pragma unroll
                for (int g = 0; g < 4; g++) {
                    float mx = -3.4e38f;
#pragma unroll
                    for (int j = 0; j < 8; j++) mx = fmaxf(mx, sacc[i][j][g]);
                    mx *= 0.125f;
#pragma unroll
                    for (int msk = 1; msk <= 8; msk <<= 1) mx = fmaxf(mx, __shfl_xor(mx, msk, 64));
                    float mnew = fmaxf(mrow[i][g], mx);
                    float alpha = __expf(mrow[i][g] - mnew);
                    mrow[i][g] = mnew;
                    float sum = 0.f;
                    int prow = (wid * 32 + i * 16 + fq * 4 + g) * 136;
#pragma unroll
                    for (int j = 0; j < 8; j++) {
                        float p = __expf(sacc[i][j][g] * 0.125f - mnew);
                        sum += p;
                        upool[prow + j * 16 + fr] = (bf16)p;
                    }
#pragma unroll
                    for (int msk = 1; msk <= 8; msk <<= 1) sum += __shfl_xor(sum, msk, 16);
                    lrow[i][g] = lrow[i][g] * alpha + sum;
#pragma unroll
                    for (int jd = 0; jd < 4; jd++) oaccv[i][jd][g] *= alpha;
                }
            }
            __syncthreads();

#pragma unroll
            for (int s2 = 0; s2 < 4; s2++) {
                bf16x8 pa[2], vb[4];
#pragma unroll
                for (int i = 0; i < 2; i++)
                    pa[i] = *(const bf16x8*)&upool[(wid * 32 + i * 16 + fr) * 136 + s2 * 32 + fq * 8];
#pragma unroll
                for (int jd = 0; jd < 4; jd++)
                    vb[jd] = *(const bf16x8*)&vt[jd * 16 + fr][s2 * 32 + fq * 8];
#pragma unroll
                for (int i = 0; i < 2; i++)
#pragma unroll
                    for (int jd = 0; jd < 4; jd++)
                        oaccv[i][jd] = __builtin_amdgcn_mfma_f32_16x16x32_bf16(pa[i], vb[jd], oaccv[i][jd], 0, 0, 0);
            }
        }

        if (pass == 0) {
#pragma unroll
            for (int i = 0; i < 2; i++)
#pragma unroll
                for (int jd = 0; jd < 4; jd++)
#pragma unroll
                    for (int g = 0; g < 4; g++)
                        o1[i][jd][g] = oaccv[i][jd][g] / lrow[i][g];
        } else {
#pragma unroll
            for (int i = 0; i < 2; i++)
#pragma unroll
                for (int jd = 0; jd < 4; jd++)
#pragma unroll
                    for (int g = 0; g < 4; g++) {
                        float dd = o1[i][jd][g] - oaccv[i][jd][g] / lrow[i][g];
                        local += dd * dd;
                    }
        }
    }

#pragma unroll
    for (int off = 32; off; off >>= 1) local += __shfl_xor(local, off, 64);
    if (lane == 0) wred[wid] = local;
    __syncthreads();
    if (tid == 0)
        partials[(long)blockIdx.y * 4 + blockIdx.x] = wred[0] + wred[1] + wred[2] + wred[3];
}

__global__ __launch_bounds__(256)
void aux_reduce_kernel(const float* __restrict__ partials, float* __restrict__ out)
{
    int tid = threadIdx.x;
    __shared__ float wred[4];
    float s = 0.f;
    for (int i = tid; i < 512; i += 256) s += partials[i];
#pragma unroll
    for (int off = 32; off; off >>= 1) s += __shfl_xor(s, off, 64);
    if ((tid & 63) == 0) wred[tid >> 6] = s;
    __syncthreads();
    if (tid == 0) out[0] = (wred[0] + wred[1] + wred[2] + wred[3]) * (1.0f / 4194304.0f);
}

__global__ __launch_bounds__(256)
void copy_kernel(float* __restrict__ dst, const float* __restrict__ src, int n4)
{
    int i = blockIdx.x * 256 + threadIdx.x;
    int stride = gridDim.x * 256;
    for (; i < n4; i += stride) {
        f32x4 v = reinterpret_cast<const f32x4*>(src)[i];
        __builtin_nontemporal_store(v, &reinterpret_cast<f32x4*>(dst)[i]);
    }
}

extern "C" void kernel_launch(void* const* d_in, const int* in_sizes, int n_in,
                              void* d_out, int out_size, void* d_ws, size_t ws_size,
                              hipStream_t stream)
{
    const float* x      = (const float*)d_in[0];
    const float* mem    = (const float*)d_in[1];
    const float* cmem   = (const float*)d_in[2];
    const float* pe     = (const float*)d_in[3];
    const float* Wq     = (const float*)d_in[4];
    const float* Wkv    = (const float*)d_in[5];
    const float* Wout   = (const float*)d_in[6];
    const float* bout   = (const float*)d_in[7];
    const float* conv_w = (const float*)d_in[8];
    const float* conv_b = (const float*)d_in[9];

    float* out_logits  = (float*)d_out;                 // 8*512*1024
    float* out_newmem  = out_logits + 4194304;          // 8*512*1024
    float* out_newcmem = out_newmem + 4194304;          // 8*128*1024
    float* out_aux     = out_newcmem + 1048576;         // 1
    float* out_weights = out_aux + 1;                   // 8*16*512*1152

    float* ws       = (float*)d_ws;
    float* partials = ws;                    // 4096 f
    bf16* bws     = (bf16*)(partials + 4096);
    bf16* WqTb    = bws;                     // 1,048,576
    bf16* WkvTb   = WqTb + 1048576;          // 2,097,152
    bf16* WoutTb  = WkvTb + 2097152;         // 1,048,576
    bf16* convwTb = WoutTb + 1048576;        // 4,194,304
    bf16* vTb     = convwTb + 4194304;       // 9,437,184
    bf16* cvT     = vTb + 9437184;           // 1,048,576
    bf16* qb      = cvT + 1048576;           // 4,194,304
    bf16* kb      = qb + 4194304;            // 9,437,184
    bf16* ckb     = kb + 9437184;            // 1,048,576
    bf16* peb     = ckb + 1048576;           // 1,179,648
    bf16* xb      = peb + 1179648;           // 4,194,304
    bf16* memb    = xb + 4194304;            // 4,194,304
    bf16* cmemb   = memb + 4194304;          // 1,048,576
    bf16* ncmemb  = cmemb + 1048576;         // 1,048,576
    bf16* oatb    = ncmemb + 1048576;        // 4,194,304

    dim3 blk(256);

    transpose_cast<<<dim3(32, 32), blk, 0, stream>>>(Wq, WqTb, 1024, 1024);
    transpose_cast<<<dim3(64, 32), blk, 0, stream>>>(Wkv, WkvTb, 1024, 2048);
    transpose_cast<<<dim3(32, 32), blk, 0, stream>>>(Wout, WoutTb, 1024, 1024);
    convw_cast<<<dim3(1024), blk, 0, stream>>>(conv_w, convwTb);
    cast_f2b<<<dim3(1152), blk, 0, stream>>>(pe, peb, 294912);
    cast_f2b<<<dim3(2048), blk, 0, stream>>>(x, xb, 1048576);
    cast_f2b<<<dim3(2048), blk, 0, stream>>>(mem, memb, 1048576);
    cast_f2b<<<dim3(1024), blk, 0, stream>>>(cmem, cmemb, 262144);

    // qb = bf16(x @ Wq)
    mfma_gemm<0, 4><<<dim3(8, 32, 1), blk, 0, stream>>>(
        xb, WqTb, nullptr, qb, nullptr, 1024, 1024, 1024, 1024, 1024,
        nullptr, 0, nullptr, nullptr, nullptr);

    // kb/vTb = bf16(concat(cmem,mem,x) @ Wkv)
    mfma_gemm<1, 5><<<dim3(16, 72, 1), blk, 0, stream>>>(
        nullptr, WkvTb, nullptr, kb, vTb, 2048, 1024, 1024, 1024, 2048,
        nullptr, 1152, cmemb, memb, xb);

    // new_cmem = mem[1024x4096] @ convwT + conv_b  (fp32 output + bf16 ncmemb)
    mfma_gemm<0, 7><<<dim3(8, 8, 1), blk, 0, stream>>>(
        memb, convwTb, out_newcmem, ncmemb, nullptr, 1024, 4096, 4096, 4096, 1024,
        conv_b, 0, nullptr, nullptr, nullptr);

    // ckb/cvT = bf16(new_cmem @ Wkv)
    mfma_gemm<0, 5><<<dim3(16, 8, 1), blk, 0, stream>>>(
        ncmemb, WkvTb, nullptr, ckb, cvT, 2048, 1024, 1024, 1024, 2048,
        nullptr, 128, nullptr, nullptr, nullptr);

    // fused attention: dots(+pos shift) -> softmax -> weights + oatb (bf16)
    attn_fused16<<<dim3(32, 128), blk, 0, stream>>>(qb, kb, peb, vTb, out_weights, oatb);

    // logits = oat @ Wout + bout (non-temporal output)
    mfma_gemm<0, 6><<<dim3(8, 32, 1), blk, 0, stream>>>(
        oatb, WoutTb, out_logits, nullptr, nullptr, 1024, 1024, 1024, 1024, 1024,
        bout, 0, nullptr, nullptr, nullptr);

    // new_mem = x (non-temporal)
    copy_kernel<<<dim3(4096), blk, 0, stream>>>(out_newmem, x, 1048576);

    // aux loss
    aux_mfma_kernel<<<dim3(4, 128), blk, 0, stream>>>(qb, kb, ckb, vTb, cvT, partials);
    aux_reduce_kernel<<<dim3(1), blk, 0, stream>>>(partials, out_aux);
}

// Round 9
// 678.939 us; speedup vs baseline: 2.2948x; 1.0175x over previous
//
#include <hip/hip_runtime.h>
#include <cstdint>

// HEADS=16, DIM=1024, SEQ=512, MEM=512, CMEM=128, RATIO=4, DIM_H=64, b=8, kv_len=1152

typedef __bf16 bf16;
typedef __bf16 bf16x4 __attribute__((ext_vector_type(4)));
typedef __bf16 bf16x8 __attribute__((ext_vector_type(8)));
typedef float  f32x4  __attribute__((ext_vector_type(4)));

// ---------------------------------------------------------------------------
// MFMA GEMM: C[M,N] = A[M,K] @ B[K,N], tile 128x128, BK=32, 4 waves.
// A: bf16 row-major (AMODE0) or concat-gather rows of cmemb/memb/xb (AMODE1).
// B: bf16 BT layout [N][K].
// EPI 0: fp32 C (+bias)
// EPI 4: bf16-only output: outB[r*ldc + c]
// EPI 5: bf16 outB[r*1024+c] for c<1024, bf16 vT for c>=1024 (row mod vrows)
// EPI 6: fp32 C (+bias), non-temporal store
// EPI 7: fp32 C (+bias) AND bf16 outB[r*1024+c]
// ---------------------------------------------------------------------------
template<int AMODE, int EPI>
__global__ __launch_bounds__(256)
void mfma_gemm(const bf16* __restrict__ A, const bf16* __restrict__ B2,
               float* __restrict__ C, bf16* __restrict__ outB, bf16* __restrict__ vT,
               int N, int K, int lda, int ldbt, int ldc,
               const float* __restrict__ bias, int vrows,
               const bf16* __restrict__ gcmem, const bf16* __restrict__ gmem,
               const bf16* __restrict__ gx)
{
    int row0 = blockIdx.y * 128, col0 = blockIdx.x * 128;
    int tid = threadIdx.x;

    __shared__ bf16 As[128][72];
    __shared__ bf16 Bs[128][72];

    int rn_ = tid >> 2;           // 0..63
    int c8  = (tid & 3) * 8;      // k-chunk (bf16)

    const bf16* aptr[2];
#pragma unroll
    for (int jj = 0; jj < 2; jj++) {
        int gr = row0 + rn_ + 64 * jj;
        if (AMODE == 0) {
            aptr[jj] = A + (long)gr * lda;
        } else {
            int bb = gr / 1152, rr = gr - bb * 1152;
            aptr[jj] = (rr < 128) ? (gcmem + ((long)bb * 128 + rr) * 1024)
                     : (rr < 640) ? (gmem + ((long)bb * 512 + (rr - 128)) * 1024)
                                  : (gx   + ((long)bb * 512 + (rr - 640)) * 1024);
        }
    }
    const bf16* bptr[2];
#pragma unroll
    for (int jj = 0; jj < 2; jj++) {
        int gc = col0 + rn_ + 64 * jj;
        bptr[jj] = (gc < N) ? (B2 + (long)gc * ldbt + c8) : nullptr;
    }

    int lane = tid & 63, wid = tid >> 6;
    int wr = wid >> 1, wc = wid & 1;
    int fr = lane & 15, fq = lane >> 4;

    f32x4 acc[4][4];
#pragma unroll
    for (int i = 0; i < 4; i++)
#pragma unroll
        for (int j = 0; j < 4; j++) acc[i][j] = (f32x4){0.f, 0.f, 0.f, 0.f};

    for (int k0 = 0; k0 < K; k0 += 32) {
#pragma unroll
        for (int jj = 0; jj < 2; jj++) {
            bf16x8 v = *(const bf16x8*)(aptr[jj] + k0 + c8);
            *(bf16x8*)&As[rn_ + 64 * jj][c8] = v;
        }
#pragma unroll
        for (int jj = 0; jj < 2; jj++) {
            bf16x8 v = {};
            if (bptr[jj]) v = *(const bf16x8*)(bptr[jj] + k0);
            *(bf16x8*)&Bs[rn_ + 64 * jj][c8] = v;
        }
        __syncthreads();

        bf16x8 af[4], bfv[4];
#pragma unroll
        for (int i = 0; i < 4; i++)
            af[i] = *(const bf16x8*)&As[wr * 64 + i * 16 + fr][fq * 8];
#pragma unroll
        for (int j = 0; j < 4; j++)
            bfv[j] = *(const bf16x8*)&Bs[wc * 64 + j * 16 + fr][fq * 8];
#pragma unroll
        for (int i = 0; i < 4; i++)
#pragma unroll
            for (int j = 0; j < 4; j++)
                acc[i][j] = __builtin_amdgcn_mfma_f32_16x16x32_bf16(af[i], bfv[j], acc[i][j], 0, 0, 0);
        __syncthreads();
    }

#pragma unroll
    for (int i = 0; i < 4; i++) {
#pragma unroll
        for (int j = 0; j < 4; j++) {
#pragma unroll
            for (int g = 0; g < 4; g++) {
                int r = row0 + wr * 64 + i * 16 + fq * 4 + g;
                int c = col0 + wc * 64 + j * 16 + fr;
                float v = acc[i][j][g];
                if (EPI == 0) {
                    if (c < N) {
                        if (bias) v += bias[c];
                        C[(long)r * ldc + c] = v;
                    }
                } else if (EPI == 6) {
                    if (c < N) {
                        if (bias) v += bias[c];
                        __builtin_nontemporal_store(v, &C[(long)r * ldc + c]);
                    }
                } else if (EPI == 7) {
                    if (c < N) {
                        if (bias) v += bias[c];
                        C[(long)r * ldc + c] = v;
                        outB[(long)r * 1024 + c] = (bf16)v;
                    }
                } else if (EPI == 4) {
                    if (c < N) outB[(long)r * ldc + c] = (bf16)v;
                } else { // EPI == 5
                    if (c < 1024) {
                        outB[(long)r * 1024 + c] = (bf16)v;
                    } else {
                        int d = c - 1024; int hh = d >> 6; d &= 63;
                        int bb = r / vrows; int j2 = r - bb * vrows;
                        vT[(((long)(bb * 16 + hh)) * 64 + d) * vrows + j2] = (bf16)v;
                    }
                }
            }
        }
    }
}

// fp32 [R][C] -> bf16 [C][R]
__global__ __launch_bounds__(256)
void transpose_cast(const float* __restrict__ in, bf16* __restrict__ out, int R, int C)
{
    __shared__ float t[32][33];
    int c0 = blockIdx.x * 32, r0 = blockIdx.y * 32;
    int tx = threadIdx.x & 31, ty = threadIdx.x >> 5;
#pragma unroll
    for (int i = 0; i < 32; i += 8)
        t[ty + i][tx] = in[(long)(r0 + ty + i) * C + c0 + tx];
    __syncthreads();
#pragma unroll
    for (int i = 0; i < 32; i += 8)
        out[(long)(c0 + ty + i) * R + r0 + tx] = (bf16)t[tx][ty + i];
}

// conv_w [o][i][r] -> bf16 [o][r*1024+i]
__global__ __launch_bounds__(256)
void convw_cast(const float* __restrict__ cw, bf16* __restrict__ out)
{
    long o = blockIdx.x;
    const float* src = cw + o * 4096;
    bf16* dst = out + o * 4096;
    for (int d = threadIdx.x; d < 4096; d += 256)
        dst[d] = (bf16)src[((d & 1023) << 2) | (d >> 10)];
}

// elementwise fp32 -> bf16 (vectorized by 4)
__global__ __launch_bounds__(256)
void cast_f2b(const float* __restrict__ in, bf16* __restrict__ out, int n4)
{
    int i = blockIdx.x * 256 + threadIdx.x;
    int stride = gridDim.x * 256;
    for (; i < n4; i += stride) {
        float4 f = reinterpret_cast<const float4*>(in)[i];
        bf16x4 h = { (bf16)f.x, (bf16)f.y, (bf16)f.z, (bf16)f.w };
        reinterpret_cast<bf16x4*>(out)[i] = h;
    }
}

// ---------------------------------------------------------------------------
// Fused attention, 16 q-rows per block, 4 waves. XCD-chunked block swizzle:
// each XCD owns 16 consecutive z (b,h) values -> k/vT panels stay in its L2.
// ---------------------------------------------------------------------------
#define SSTR 1164

__global__ __launch_bounds__(256)
void attn_fused16(const bf16* __restrict__ qb, const bf16* __restrict__ kb,
                  const bf16* __restrict__ peb, const bf16* __restrict__ vTb,
                  float* __restrict__ weights, bf16* __restrict__ oatb)
{
    // bijective XCD swizzle: 4096 blocks = 8 XCD x 512; z-major within XCD
    int bid = blockIdx.x;
    int w = (bid & 7) * 512 + (bid >> 3);
    int z = w >> 5;                  // b*16 + h
    int b = z >> 4, h = z & 15;
    int r0 = (w & 31) * 16;
    int tid = threadIdx.x;
    int lane = tid & 63, wid = tid >> 6;
    int fr = lane & 15, fq = lane >> 4;

    __shared__ bf16 S[16 * SSTR];      // 37.2 KB

    // q fragments direct from global
    bf16x8 afr[2];
#pragma unroll
    for (int ks = 0; ks < 2; ks++)
        afr[ks] = *(const bf16x8*)&qb[((long)(b * 512 + r0 + fr)) * 1024 + h * 64 + ks * 32 + fq * 8];

    // ---------------- S build: 9 chunks, no cross-wave sync ----------------
#pragma unroll 3
    for (int ch = 0; ch < 9; ch++) {
        int c0 = ch * 128;
        int jb0 = c0 + 496 - r0 + 32 * wid;   // wave-local band start

        // 3 pos tiles (band cols [32w, 32w+48)) -> register fragments
        f32x4 p[3];
#pragma unroll
        for (int ct = 0; ct < 3; ct++) {
            f32x4 a = (f32x4){0.f, 0.f, 0.f, 0.f};
            int j = jb0 + ct * 16 + fr;
            bool ok = (j < 1152);
#pragma unroll
            for (int ks = 0; ks < 2; ks++) {
                bf16x8 bv = {};
                if (ok) bv = *(const bf16x8*)&peb[((long)(h * 1152 + j)) * 64 + ks * 32 + fq * 8];
                a = __builtin_amdgcn_mfma_f32_16x16x32_bf16(afr[ks], bv, a, 0, 0, 0);
            }
            p[ct] = a;
        }

        // 2 qk tiles; shifted pos via cross-lane shuffle from p[] fragments
#pragma unroll
        for (int tt = 0; tt < 2; tt++) {
            int cc = 32 * wid + 16 * tt + fr;
            f32x4 a = (f32x4){0.f, 0.f, 0.f, 0.f};
            long krow = (long)(b * 1152 + c0 + cc);
#pragma unroll
            for (int ks = 0; ks < 2; ks++) {
                bf16x8 bv = *(const bf16x8*)&kb[krow * 1024 + h * 64 + ks * 32 + fq * 8];
                a = __builtin_amdgcn_mfma_f32_16x16x32_bf16(afr[ks], bv, a, 0, 0, 0);
            }
#pragma unroll
            for (int g = 0; g < 4; g++) {
                int rr = fq * 4 + g;
                int uu = fr + 15 - rr;                 // 0..30
                int src = (uu & 15) | (fq << 4);
                float s0 = __shfl(p[tt][g], src, 64);
                float s1 = __shfl(p[tt + 1][g], src, 64);
                float pv = (uu < 16) ? s0 : s1;
                S[rr * SSTR + c0 + cc] = (bf16)(0.125f * (a[g] + pv));
            }
        }
    }
    __syncthreads();

    // ---------------- softmax: 4 waves x 4 rows ----------------
    for (int rw = 0; rw < 4; rw++) {
        int row = wid * 4 + rw;
        float ebuf[18];
        float m = -3.4e38f;
#pragma unroll
        for (int k = 0; k < 18; k++) {
            float v = (float)S[row * SSTR + lane + 64 * k];
            ebuf[k] = v; m = fmaxf(m, v);
        }
#pragma unroll
        for (int off = 32; off; off >>= 1) m = fmaxf(m, __shfl_xor(m, off, 64));
        float sm = 0.f;
#pragma unroll
        for (int k = 0; k < 18; k++) { float e = __expf(ebuf[k] - m); ebuf[k] = e; sm += e; }
#pragma unroll
        for (int off = 32; off; off >>= 1) sm += __shfl_xor(sm, off, 64);
        float inv = 1.f / sm;
        long wbase = ((long)z * 512 + r0 + row) * 1152 + lane;
#pragma unroll
        for (int k = 0; k < 18; k++) {
            float pv = ebuf[k] * inv;
            __builtin_nontemporal_store(pv, &weights[wbase + 64 * k]);
            S[row * SSTR + lane + 64 * k] = (bf16)pv;
        }
    }
    __syncthreads();

    // ---------------- PV: wave wid owns d-tile dt=wid; output bf16 ----------------
    f32x4 oacc = (f32x4){0.f, 0.f, 0.f, 0.f};
    int dt = wid;
    for (int ch = 0; ch < 9; ch++) {
        int c0 = ch * 128;
#pragma unroll
        for (int ks = 0; ks < 4; ks++) {
            bf16x8 pa = *(const bf16x8*)&S[fr * SSTR + c0 + ks * 32 + fq * 8];
            bf16x8 vb = *(const bf16x8*)&vTb[((long)z * 64 + dt * 16 + fr) * 1152 + c0 + ks * 32 + fq * 8];
            oacc = __builtin_amdgcn_mfma_f32_16x16x32_bf16(pa, vb, oacc, 0, 0, 0);
        }
    }
#pragma unroll
    for (int g = 0; g < 4; g++)
        oatb[((long)(b * 512 + r0 + fq * 4 + g)) * 1024 + h * 64 + dt * 16 + fr] = (bf16)oacc[g];
}

// ---------------------------------------------------------------------------
// Fused MFMA aux loss (bf16-staged sources)
// ---------------------------------------------------------------------------
__global__ __launch_bounds__(256)
void aux_mfma_kernel(const bf16* __restrict__ qb, const bf16* __restrict__ kb,
                     const bf16* __restrict__ ckb,
                     const bf16* __restrict__ vTb, const bf16* __restrict__ cvT,
                     float* __restrict__ partials)
{
    int z = blockIdx.y;
    int b = z >> 4, h = z & 15;
    int r0 = blockIdx.x * 128;
    int tid = threadIdx.x;
    int lane = tid & 63, wid = tid >> 6;
    int fr = lane & 15, fq = lane >> 4;

    __shared__ bf16 qs[128][72];
    __shared__ bf16 upool[128 * 136];
    __shared__ bf16 vt[64][136];
    __shared__ float wred[4];

#pragma unroll
    for (int t = 0; t < 4; t++) {
        int e = tid + 256 * t; int rr = e >> 3, c8 = (e & 7) * 8;
        *(bf16x8*)&qs[rr][c8] = *(const bf16x8*)&qb[((long)(b * 512 + r0 + rr)) * 1024 + h * 64 + c8];
    }

    float o1[2][4][4];
    f32x4 oaccv[2][4];
    float mrow[2][4], lrow[2][4];
    f32x4 sacc[2][8];
    float local = 0.f;

    for (int pass = 0; pass < 2; pass++) {
#pragma unroll
        for (int i = 0; i < 2; i++)
#pragma unroll
            for (int g = 0; g < 4; g++) { mrow[i][g] = -3.4e38f; lrow[i][g] = 0.f; }
#pragma unroll
        for (int i = 0; i < 2; i++)
#pragma unroll
            for (int jd = 0; jd < 4; jd++) oaccv[i][jd] = (f32x4){0.f, 0.f, 0.f, 0.f};

        int nchunk = pass ? 1 : 4;
        for (int jt = 0; jt < nchunk; jt++) {
            __syncthreads();
            if (pass == 0) {
                long base = (long)(b * 1152 + 128 + jt * 128);
#pragma unroll
                for (int t = 0; t < 4; t++) {
                    int e = tid + 256 * t; int j = e >> 3, c8 = (e & 7) * 8;
                    *(bf16x8*)&upool[j * 72 + c8] = *(const bf16x8*)&kb[(base + j) * 1024 + h * 64 + c8];
                }
#pragma unroll
                for (int t = 0; t < 4; t++) {
                    int e = tid + 256 * t; int d = e >> 4, j8 = (e & 15) * 8;
                    *(bf16x8*)&vt[d][j8] =
                        *(const bf16x8*)&vTb[((long)z * 64 + d) * 1152 + 128 + jt * 128 + j8];
                }
            } else {
#pragma unroll
                for (int t = 0; t < 4; t++) {
                    int e = tid + 256 * t; int j = e >> 3, c8 = (e & 7) * 8;
                    *(bf16x8*)&upool[j * 72 + c8] = *(const bf16x8*)&ckb[((long)(b * 128 + j)) * 1024 + h * 64 + c8];
                }
#pragma unroll
                for (int t = 0; t < 4; t++) {
                    int e = tid + 256 * t; int d = e >> 4, j8 = (e & 15) * 8;
                    *(bf16x8*)&vt[d][j8] = *(const bf16x8*)&cvT[((long)z * 64 + d) * 128 + j8];
                }
            }
            __syncthreads();

#pragma unroll
            for (int i = 0; i < 2; i++)
#pragma unroll
                for (int j = 0; j < 8; j++) sacc[i][j] = (f32x4){0.f, 0.f, 0.f, 0.f};
#pragma unroll
            for (int s = 0; s < 2; s++) {
                bf16x8 af[2], bfv[8];
#pragma unroll
                for (int i = 0; i < 2; i++)
                    af[i] = *(const bf16x8*)&qs[wid * 32 + i * 16 + fr][s * 32 + fq * 8];
#pragma unroll
                for (int j = 0; j < 8; j++)
                    bfv[j] = *(const bf16x8*)&upool[(j * 16 + fr) * 72 + s * 32 + fq * 8];
#pragma unroll
                for (int i = 0; i < 2; i++)
#pragma unroll
                    for (int j = 0; j < 8; j++)
                        sacc[i][j] = __builtin_amdgcn_mfma_f32_16x16x32_bf16(af[i], bfv[j], sacc[i][j], 0, 0, 0);
            }
            __syncthreads();

#pragma unroll
            for (int i = 0; i < 2; i++) {
#pragma unroll
                for (int g = 0; g < 4; g++) {
                    float mx = -3.4e38f;
#pragma unroll
                    for (int j = 0; j < 8; j++) mx = fmaxf(mx, sacc[i][j][g]);
                    mx *= 0.125f;
#pragma unroll
                    for (int msk = 1; msk <= 8; msk <<= 1) mx = fmaxf(mx, __shfl_xor(mx, msk, 64));
                    float mnew = fmaxf(mrow[i][g], mx);
                    float alpha = __expf(mrow[i][g] - mnew);
                    mrow[i][g] = mnew;
                    float sum = 0.f;
                    int prow = (wid * 32 + i * 16 + fq * 4 + g) * 136;
#pragma unroll
                    for (int j = 0; j < 8; j++) {
                        float p = __expf(sacc[i][j][g] * 0.125f - mnew);
                        sum += p;
                        upool[prow + j * 16 + fr] = (bf16)p;
                    }
#pragma unroll
                    for (int msk = 1; msk <= 8; msk <<= 1) sum += __shfl_xor(sum, msk, 16);
                    lrow[i][g] = lrow[i][g] * alpha + sum;
#pragma unroll
                    for (int jd = 0; jd < 4; jd++) oaccv[i][jd][g] *= alpha;
                }
            }
            __syncthreads();

#pragma unroll
            for (int s2 = 0; s2 < 4; s2++) {
                bf16x8 pa[2], vb[4];
#pragma unroll
                for (int i = 0; i < 2; i++)
                    pa[i] = *(const bf16x8*)&upool[(wid * 32 + i * 16 + fr) * 136 + s2 * 32 + fq * 8];
#pragma unroll
                for (int jd = 0; jd < 4; jd++)
                    vb[jd] = *(const bf16x8*)&vt[jd * 16 + fr][s2 * 32 + fq * 8];
#pragma unroll
                for (int i = 0; i < 2; i++)
#pragma unroll
                    for (int jd = 0; jd < 4; jd++)
                        oaccv[i][jd] = __builtin_amdgcn_mfma_f32_16x16x32_bf16(pa[i], vb[jd], oaccv[i][jd], 0, 0, 0);
            }
        }

        if (pass == 0) {
#pragma unroll
            for (int i = 0; i < 2; i++)
#pragma unroll
                for (int jd = 0; jd < 4; jd++)
#pragma unroll
                    for (int g = 0; g < 4; g++)
                        o1[i][jd][g] = oaccv[i][jd][g] / lrow[i][g];
        } else {
#pragma unroll
            for (int i = 0; i < 2; i++)
#pragma unroll
                for (int jd = 0; jd < 4; jd++)
#pragma unroll
                    for (int g = 0; g < 4; g++) {
                        float dd = o1[i][jd][g] - oaccv[i][jd][g] / lrow[i][g];
                        local += dd * dd;
                    }
        }
    }

#pragma unroll
    for (int off = 32; off; off >>= 1) local += __shfl_xor(local, off, 64);
    if (lane == 0) wred[wid] = local;
    __syncthreads();
    if (tid == 0)
        partials[(long)blockIdx.y * 4 + blockIdx.x] = wred[0] + wred[1] + wred[2] + wred[3];
}

__global__ __launch_bounds__(256)
void aux_reduce_kernel(const float* __restrict__ partials, float* __restrict__ out)
{
    int tid = threadIdx.x;
    __shared__ float wred[4];
    float s = 0.f;
    for (int i = tid; i < 512; i += 256) s += partials[i];
#pragma unroll
    for (int off = 32; off; off >>= 1) s += __shfl_xor(s, off, 64);
    if ((tid & 63) == 0) wred[tid >> 6] = s;
    __syncthreads();
    if (tid == 0) out[0] = (wred[0] + wred[1] + wred[2] + wred[3]) * (1.0f / 4194304.0f);
}

__global__ __launch_bounds__(256)
void copy_kernel(float* __restrict__ dst, const float* __restrict__ src, int n4)
{
    int i = blockIdx.x * 256 + threadIdx.x;
    int stride = gridDim.x * 256;
    for (; i < n4; i += stride) {
        f32x4 v = reinterpret_cast<const f32x4*>(src)[i];
        __builtin_nontemporal_store(v, &reinterpret_cast<f32x4*>(dst)[i]);
    }
}

extern "C" void kernel_launch(void* const* d_in, const int* in_sizes, int n_in,
                              void* d_out, int out_size, void* d_ws, size_t ws_size,
                              hipStream_t stream)
{
    const float* x      = (const float*)d_in[0];
    const float* mem    = (const float*)d_in[1];
    const float* cmem   = (const float*)d_in[2];
    const float* pe     = (const float*)d_in[3];
    const float* Wq     = (const float*)d_in[4];
    const float* Wkv    = (const float*)d_in[5];
    const float* Wout   = (const float*)d_in[6];
    const float* bout   = (const float*)d_in[7];
    const float* conv_w = (const float*)d_in[8];
    const float* conv_b = (const float*)d_in[9];

    float* out_logits  = (float*)d_out;                 // 8*512*1024
    float* out_newmem  = out_logits + 4194304;          // 8*512*1024
    float* out_newcmem = out_newmem + 4194304;          // 8*128*1024
    float* out_aux     = out_newcmem + 1048576;         // 1
    float* out_weights = out_aux + 1;                   // 8*16*512*1152

    float* ws       = (float*)d_ws;
    float* partials = ws;                    // 4096 f
    bf16* bws     = (bf16*)(partials + 4096);
    bf16* WqTb    = bws;                     // 1,048,576
    bf16* WkvTb   = WqTb + 1048576;          // 2,097,152
    bf16* WoutTb  = WkvTb + 2097152;         // 1,048,576
    bf16* convwTb = WoutTb + 1048576;        // 4,194,304
    bf16* vTb     = convwTb + 4194304;       // 9,437,184
    bf16* cvT     = vTb + 9437184;           // 1,048,576
    bf16* qb      = cvT + 1048576;           // 4,194,304
    bf16* kb      = qb + 4194304;            // 9,437,184
    bf16* ckb     = kb + 9437184;            // 1,048,576
    bf16* peb     = ckb + 1048576;           // 1,179,648
    bf16* xb      = peb + 1179648;           // 4,194,304
    bf16* memb    = xb + 4194304;            // 4,194,304
    bf16* cmemb   = memb + 4194304;          // 1,048,576
    bf16* ncmemb  = cmemb + 1048576;         // 1,048,576
    bf16* oatb    = ncmemb + 1048576;        // 4,194,304

    dim3 blk(256);

    transpose_cast<<<dim3(32, 32), blk, 0, stream>>>(Wq, WqTb, 1024, 1024);
    transpose_cast<<<dim3(64, 32), blk, 0, stream>>>(Wkv, WkvTb, 1024, 2048);
    transpose_cast<<<dim3(32, 32), blk, 0, stream>>>(Wout, WoutTb, 1024, 1024);
    convw_cast<<<dim3(1024), blk, 0, stream>>>(conv_w, convwTb);
    cast_f2b<<<dim3(1152), blk, 0, stream>>>(pe, peb, 294912);
    cast_f2b<<<dim3(2048), blk, 0, stream>>>(x, xb, 1048576);
    cast_f2b<<<dim3(2048), blk, 0, stream>>>(mem, memb, 1048576);
    cast_f2b<<<dim3(1024), blk, 0, stream>>>(cmem, cmemb, 262144);

    // qb = bf16(x @ Wq)
    mfma_gemm<0, 4><<<dim3(8, 32, 1), blk, 0, stream>>>(
        xb, WqTb, nullptr, qb, nullptr, 1024, 1024, 1024, 1024, 1024,
        nullptr, 0, nullptr, nullptr, nullptr);

    // kb/vTb = bf16(concat(cmem,mem,x) @ Wkv)
    mfma_gemm<1, 5><<<dim3(16, 72, 1), blk, 0, stream>>>(
        nullptr, WkvTb, nullptr, kb, vTb, 2048, 1024, 1024, 1024, 2048,
        nullptr, 1152, cmemb, memb, xb);

    // new_cmem = mem[1024x4096] @ convwT + conv_b  (fp32 output + bf16 ncmemb)
    mfma_gemm<0, 7><<<dim3(8, 8, 1), blk, 0, stream>>>(
        memb, convwTb, out_newcmem, ncmemb, nullptr, 1024, 4096, 4096, 4096, 1024,
        conv_b, 0, nullptr, nullptr, nullptr);

    // ckb/cvT = bf16(new_cmem @ Wkv)
    mfma_gemm<0, 5><<<dim3(16, 8, 1), blk, 0, stream>>>(
        ncmemb, WkvTb, nullptr, ckb, cvT, 2048, 1024, 1024, 1024, 2048,
        nullptr, 128, nullptr, nullptr, nullptr);

    // fused attention with XCD-chunked swizzle
    attn_fused16<<<dim3(4096), blk, 0, stream>>>(qb, kb, peb, vTb, out_weights, oatb);

    // logits = oat @ Wout + bout (non-temporal output)
    mfma_gemm<0, 6><<<dim3(8, 32, 1), blk, 0, stream>>>(
        oatb, WoutTb, out_logits, nullptr, nullptr, 1024, 1024, 1024, 1024, 1024,
        bout, 0, nullptr, nullptr, nullptr);

    // new_mem = x (non-temporal)
    copy_kernel<<<dim3(4096), blk, 0, stream>>>(out_newmem, x, 1048576);

    // aux loss
    aux_mfma_kernel<<<dim3(4, 128), blk, 0, stream>>>(qb, kb, ckb, vTb, cvT, partials);
    aux_reduce_kernel<<<dim3(1), blk, 0, stream>>>(partials, out_aux);
}